// Round 10
// baseline (228.356 us; speedup 1.0000x reference)
//
#include <hip/hip_runtime.h>
#include <hip/hip_bf16.h>

// Problem constants (fixed by the reference file)
#define LEAFN 1024
#define NN    2048            // nodes per batch incl. global node 0
#define BATCH 8
#define DD    128
#define ROWS  (BATCH*NN)      // 16384
#define AHS   384             // ah row stride: [agg(128) | hL0(128) | hL1(128)]
#define NB    256             // megakernel grid (1 block/CU)
#define NT    512             // threads per block (8 waves)

// ln(10000)/32
#define LOG1E4_OVER_32 0.28782313662425575f

typedef __bf16 bf16x8 __attribute__((ext_vector_type(8)));
typedef float  floatx4 __attribute__((ext_vector_type(4)));
typedef float  floatx2 __attribute__((ext_vector_type(2)));

__device__ __forceinline__ float bf2f(unsigned short u) {
  return __uint_as_float(((unsigned)u) << 16);
}
__device__ __forceinline__ unsigned short f2bf(float f) {
  unsigned u = __float_as_uint(f);
  u += 0x7FFFu + ((u >> 16) & 1u);          // round-to-nearest-even
  return (unsigned short)(u >> 16);
}
__device__ __forceinline__ float gelu(float v) {
  return 0.5f * v * (1.0f + erff(v * 0.70710678118f));
}
__device__ __forceinline__ floatx2 bfpair(unsigned u) {
  floatx2 r;
  r[0] = __uint_as_float(u << 16);
  r[1] = __uint_as_float(u & 0xffff0000u);
  return r;
}

__device__ __forceinline__ float enc_val(int node, int d) {
  float hp, vp;
  if (node == 0) { hp = -0.5f; vp = -1.0f; }
  else {
    int v = 31 - __clz(node);
    hp = (float)(node - (1 << v));
    vp = (float)v;
  }
  float pos = (d < 64) ? hp : vp;
  int i = ((d < 64) ? d : (d - 64)) >> 1;
  float inv = expf(-(float)i * LOG1E4_OVER_32);
  float ang = pos * inv;
  return (d & 1) ? cosf(ang) : sinf(ang);
}

// ---------------------------------------------------------------------------
// Per-group barrier over n participants (group g = bid>>5 = batch).
__device__ __forceinline__ void gbarN(int* bar, int slot, int n) {
  __syncthreads();
  if (threadIdx.x == 0) {
    int g = blockIdx.x >> 5;
    int* base = bar + (slot * 8 + g) * 64;
    __threadfence();                           // release (L2 wb)
    if (__hip_atomic_fetch_add(base, 1, __ATOMIC_RELAXED,
                               __HIP_MEMORY_SCOPE_AGENT) == n - 1)
      __hip_atomic_store(base + 32, 1, __ATOMIC_RELAXED,
                         __HIP_MEMORY_SCOPE_AGENT);
    while (!__hip_atomic_load(base + 32, __ATOMIC_RELAXED,
                              __HIP_MEMORY_SCOPE_AGENT))
      __builtin_amdgcn_s_sleep(2);
    __threadfence();                           // acquire (L2 inv)
  }
  __syncthreads();
}

// ---------------------------------------------------------------------------
// Tree build + layer-0 LN/GELU + in-LDS subtree sums (agg depth 4..9).
__device__ __forceinline__ void ph_tree(char* smemc, int b, int s,
                                        const float* __restrict__ elements,
                                        float* __restrict__ x,
                                        float* __restrict__ lvl4,
                                        unsigned short* __restrict__ ah,
                                        const float* __restrict__ gamma,
                                        const float* __restrict__ beta,
                                        float* __restrict__ sroot) {
  float* sm = (float*)smemc;                  // 127*128 floats = 63.5 KB
  int tid = threadIdx.x;
  const float4* src = (const float4*)(elements + (size_t)(b * LEAFN + s * 64) * DD);
  for (int i = tid; i < 2048; i += NT) {
    int f = i * 4;
    int j = f >> 7, d = f & 127;
    *(float4*)&sm[(63 + j) * DD + d] = src[i];
  }
  __syncthreads();
  for (int lv = 5; lv >= 0; --lv) {
    int nodes = 1 << lv;
    for (int idx = tid; idx < nodes * DD; idx += NT) {
      int k = nodes + (idx >> 7);
      int d = idx & 127;
      sm[(k - 1) * DD + d] = 0.5f * (sm[(2 * k - 1) * DD + d] + sm[(2 * k) * DD + d]);
    }
    __syncthreads();
  }
  if (tid < DD) lvl4[(b * 16 + s) * DD + tid] = sm[tid];
  __syncthreads();
  for (int idx = tid; idx < 127 * DD; idx += NT) {
    int k = (idx >> 7) + 1;
    int d = idx & 127;
    int lv = 31 - __clz(k);
    int g = ((16 + s) << lv) | (k - (1 << lv));
    float xv = sm[idx] + enc_val(g, d);
    x[((size_t)(b * NN + g)) * DD + d] = xv;
    sm[idx] = xv;
  }
  __syncthreads();
  // LN + GELU: 8 threads/row; h -> ah(+128) AND h overwrites sm (fp32)
  {
    int sub = tid & 7, dp = sub * 16;
    for (int rr = tid >> 3; rr < 127; rr += NT / 8) {
      float v[16], s1 = 0.f, s2 = 0.f;
#pragma unroll
      for (int j = 0; j < 16; ++j) { v[j] = sm[rr * DD + dp + j]; s1 += v[j]; s2 += v[j] * v[j]; }
      s1 += __shfl_xor(s1, 1); s2 += __shfl_xor(s2, 1);
      s1 += __shfl_xor(s1, 2); s2 += __shfl_xor(s2, 2);
      s1 += __shfl_xor(s1, 4); s2 += __shfl_xor(s2, 4);
      float mu = s1 * (1.0f / 128.0f);
      float var = s2 * (1.0f / 128.0f) - mu * mu;
      float rinv = rsqrtf(var + 1e-5f);
      int k = rr + 1, lv = 31 - __clz(k);
      int g = ((16 + s) << lv) | (k - (1 << lv));
      __attribute__((aligned(16))) unsigned short o[16];
#pragma unroll
      for (int j = 0; j < 16; ++j) {
        float hv = gelu((v[j] - mu) * rinv * gamma[dp + j] + beta[dp + j]);
        o[j] = f2bf(hv);
        sm[rr * DD + dp + j] = hv;
      }
      unsigned short* dst = &ah[(size_t)(b * NN + g) * AHS + 128 + dp];
      *(uint4*)&dst[0] = *(uint4*)&o[0];
      *(uint4*)&dst[8] = *(uint4*)&o[8];
    }
  }
  __syncthreads();
  // subtree-sum pyramid in LDS; agg (closed-form deg) -> ah(+0)
  for (int lv = 5; lv >= 0; --lv) {
    int nk = 1 << lv;
    float inv = 1.0f / (float)((1 << (7 - lv)) - 2);
    for (int idx = tid; idx < nk * DD; idx += NT) {
      int k = nk + (idx >> 7);
      int d = idx & 127;
      float S = sm[(2 * k - 1) * DD + d] + sm[(2 * k) * DD + d];
      if (lv < 5) S += sm[(4 * k - 1) * DD + d] + sm[(4 * k + 1) * DD + d];
      sm[(2 * k - 1) * DD + d] = S;
      int g = ((16 + s) << lv) | (k - nk);
      ah[(size_t)(b * NN + g) * AHS + d] = f2bf(S * inv);
    }
    __syncthreads();
  }
  if (tid < DD) sroot[(size_t)(b * 16 + s) * DD + tid] = sm[DD + tid];
}

// ---------------------------------------------------------------------------
// Top nodes 0..15: finish tree, write x and layer-0 h (tid<128).
__device__ __forceinline__ void ph_top(char* smemc, int b,
                                       const float* __restrict__ lvl4,
                                       float* __restrict__ x,
                                       unsigned short* __restrict__ ah,
                                       const float* __restrict__ gamma,
                                       const float* __restrict__ beta) {
  float (*xs)[DD] = (float(*)[DD])smemc;      // 8 KB
  int tid = threadIdx.x;
  if (tid < 128) {
    int d = tid;
    float v[16];
    for (int j = 0; j < 16; ++j) v[j] = lvl4[(b * 16 + j) * DD + d];
    for (int j = 0; j < 8; ++j) v[j] = 0.5f * (v[2 * j] + v[2 * j + 1]);
    for (int j = 0; j < 8; ++j) xs[8 + j][d] = v[j] + enc_val(8 + j, d);
    for (int j = 0; j < 4; ++j) v[j] = 0.5f * (v[2 * j] + v[2 * j + 1]);
    for (int j = 0; j < 4; ++j) xs[4 + j][d] = v[j] + enc_val(4 + j, d);
    for (int j = 0; j < 2; ++j) v[j] = 0.5f * (v[2 * j] + v[2 * j + 1]);
    for (int j = 0; j < 2; ++j) xs[2 + j][d] = v[j] + enc_val(2 + j, d);
    v[0] = 0.5f * (v[0] + v[1]);
    xs[1][d] = v[0] + enc_val(1, d);
    xs[0][d] = -1.0f + enc_val(0, d);
    for (int j = 0; j < 16; ++j) x[((size_t)(b * NN + j)) * DD + d] = xs[j][d];
  }
  __syncthreads();
  if (tid < 128) {
    int rr = tid >> 3, sub = tid & 7, dp = sub * 16;
    float w[16], s1 = 0.f, s2 = 0.f;
#pragma unroll
    for (int j = 0; j < 16; ++j) { w[j] = xs[rr][dp + j]; s1 += w[j]; s2 += w[j] * w[j]; }
    s1 += __shfl_xor(s1, 1); s2 += __shfl_xor(s2, 1);
    s1 += __shfl_xor(s1, 2); s2 += __shfl_xor(s2, 2);
    s1 += __shfl_xor(s1, 4); s2 += __shfl_xor(s2, 4);
    float mu = s1 * (1.0f / 128.0f);
    float var = s2 * (1.0f / 128.0f) - mu * mu;
    float rinv = rsqrtf(var + 1e-5f);
    __attribute__((aligned(16))) unsigned short o[16];
#pragma unroll
    for (int j = 0; j < 16; ++j)
      o[j] = f2bf(gelu((w[j] - mu) * rinv * gamma[dp + j] + beta[dp + j]));
    unsigned short* dst = &ah[(size_t)(b * NN + rr) * AHS + 128 + dp];
    *(uint4*)&dst[0] = *(uint4*)&o[0];
    *(uint4*)&dst[8] = *(uint4*)&o[8];
  }
  __syncthreads();
}

// ---------------------------------------------------------------------------
// Subtree sums for L1: reads h' from ah(+256), agg -> ah(+0), sroot.
__device__ __forceinline__ void ph_aggsub(char* smemc, int b, int s,
                                          unsigned short* ah,
                                          float* __restrict__ sroot) {
  floatx4 (*S)[32] = (floatx4(*)[32])smemc;   // 32 KB
  int tid = threadIdx.x;
  for (int idx = tid; idx < 32 * 32; idx += NT) {
    int k = 32 + (idx >> 5), q = idx & 31;
    int c = (16 + s) * 64 + (2 * k - 64);
    size_t a0 = (size_t)(b * NN + c) * AHS + 256 + q * 4;
    ushort4 u0 = *(const ushort4*)&ah[a0];
    ushort4 u1 = *(const ushort4*)&ah[a0 + AHS];
    floatx4 v;
    v[0] = bf2f(u0.x) + bf2f(u1.x);
    v[1] = bf2f(u0.y) + bf2f(u1.y);
    v[2] = bf2f(u0.z) + bf2f(u1.z);
    v[3] = bf2f(u0.w) + bf2f(u1.w);
    S[k][q] = v;
    int g = (16 + s) * 32 + (k - 32);
    int r = b * NN + g;
    ushort4 o;
    o.x = f2bf(v[0] * 0.5f); o.y = f2bf(v[1] * 0.5f);
    o.z = f2bf(v[2] * 0.5f); o.w = f2bf(v[3] * 0.5f);
    *(ushort4*)&ah[(size_t)r * AHS + q * 4] = o;
  }
  __syncthreads();
  for (int lv = 4; lv >= 0; --lv) {
    int nk = 1 << lv;
    float inv = 1.0f / (float)((1 << (7 - lv)) - 2);
    for (int idx = tid; idx < nk * 32; idx += NT) {
      int k = nk + (idx >> 5), q = idx & 31;
      int c = ((16 + s) << (lv + 1)) | (2 * k - 2 * nk);
      size_t a0 = (size_t)(b * NN + c) * AHS + 256 + q * 4;
      ushort4 u0 = *(const ushort4*)&ah[a0];
      ushort4 u1 = *(const ushort4*)&ah[a0 + AHS];
      floatx4 sc0 = S[2 * k][q], sc1 = S[2 * k + 1][q];
      floatx4 v;
      v[0] = bf2f(u0.x) + bf2f(u1.x) + sc0[0] + sc1[0];
      v[1] = bf2f(u0.y) + bf2f(u1.y) + sc0[1] + sc1[1];
      v[2] = bf2f(u0.z) + bf2f(u1.z) + sc0[2] + sc1[2];
      v[3] = bf2f(u0.w) + bf2f(u1.w) + sc0[3] + sc1[3];
      S[k][q] = v;
      int g = ((16 + s) << lv) | (k - nk);
      int r = b * NN + g;
      ushort4 o;
      o.x = f2bf(v[0] * inv); o.y = f2bf(v[1] * inv);
      o.z = f2bf(v[2] * inv); o.w = f2bf(v[3] * inv);
      *(ushort4*)&ah[(size_t)r * AHS + q * 4] = o;
    }
    __syncthreads();
  }
  for (int q = tid; q < 32; q += NT)
    ((floatx4*)sroot)[(size_t)(b * 16 + s) * 32 + q] = S[1][q];
}

// ---------------------------------------------------------------------------
// Leaf-row gather: per-level LDS window cache; h read at +hoff; agg -> +0.
#define SLACK 10
#define CACHE_ROWS 220
#define CSTRIDE 136
__device__ __forceinline__ void ph_leafagg(char* smemc, int b, int jb,
                                           const int* __restrict__ src,
                                           const int* __restrict__ s0a,
                                           const int* __restrict__ s1a,
                                           unsigned short* ah, int hoff,
                                           const float* __restrict__ lvl4,
                                           const float* __restrict__ gamma,
                                           const float* __restrict__ beta,
                                           int l0patch) {
  unsigned short* cache = (unsigned short*)smemc;  // 59840 B
  int2* wtab = (int2*)(smemc + 60928);             // 11 entries
  int tid = threadIdx.x;
  int li0 = jb * 32;
  int g0 = 1024 + li0, g1 = g0 + 31;

  int lo[11], wd[11], off[11];
  int acc_off = 0;
  for (int cd = 10; cd >= 1; --cd) {
    int a0 = g0 >> (10 - cd), a1 = g1 >> (10 - cd);
    int l = a0 - SLACK, hgh = a1 + SLACK;
    int lvlo = 1 << cd, lvhi = (2 << cd) - 1;
    l = l < lvlo ? lvlo : l;
    hgh = hgh > lvhi ? lvhi : hgh;
    int w = hgh - l + 1;
    if (w < 0) w = 0;
    lo[cd] = l; wd[cd] = w; off[cd] = acc_off; acc_off += w;
  }
  if (tid >= 1 && tid <= 10) {
    int cd = tid;
    wtab[cd] = make_int2(off[cd] - lo[cd], lo[cd] | (wd[cd] << 16));
  }
  int cdmin = l0patch ? 4 : 1;
  for (int cd = 10; cd >= cdmin; --cd) {
    int w = wd[cd];
    for (int t = tid; t < w * 16; t += NT) {
      int row = t >> 4, seg = t & 15;
      *(uint4*)&cache[(off[cd] + row) * CSTRIDE + seg * 8] =
          *(const uint4*)&ah[(size_t)(b * NN + lo[cd] + row) * AHS + hoff + seg * 8];
    }
  }
  if (l0patch && tid < 112) {
    // h rows 2..15 computed locally from lvl4 (mean + enc + LN + GELU)
    int row = 2 + (tid >> 3), sub = tid & 7, dp = sub * 16;
    int dv = 31 - __clz(row);
    int cnt = 1 << (4 - dv);
    int l4r = (row << (4 - dv)) - 16;
    float v[16];
#pragma unroll
    for (int j = 0; j < 16; ++j) v[j] = 0.f;
    for (int c = 0; c < cnt; ++c) {
      const float* p = &lvl4[(size_t)(b * 16 + l4r + c) * DD + dp];
#pragma unroll
      for (int j = 0; j < 16; ++j) v[j] += p[j];
    }
    float sc = 1.0f / (float)cnt;
    float s1 = 0.f, s2 = 0.f;
#pragma unroll
    for (int j = 0; j < 16; ++j) {
      v[j] = v[j] * sc + enc_val(row, dp + j);
      s1 += v[j]; s2 += v[j] * v[j];
    }
    s1 += __shfl_xor(s1, 1); s2 += __shfl_xor(s2, 1);
    s1 += __shfl_xor(s1, 2); s2 += __shfl_xor(s2, 2);
    s1 += __shfl_xor(s1, 4); s2 += __shfl_xor(s2, 4);
    float mu = s1 * (1.0f / 128.0f);
    float var = s2 * (1.0f / 128.0f) - mu * mu;
    float rinv = rsqrtf(var + 1e-5f);
    __attribute__((aligned(16))) unsigned short o[16];
#pragma unroll
    for (int j = 0; j < 16; ++j)
      o[j] = f2bf(gelu((v[j] - mu) * rinv * gamma[dp + j] + beta[dp + j]));
    int cr = off[dv] + (row - lo[dv]);
    *(uint4*)&cache[cr * CSTRIDE + sub * 16] = *(uint4*)&o[0];
    *(uint4*)&cache[cr * CSTRIDE + sub * 16 + 8] = *(uint4*)&o[8];
  }
  __syncthreads();

  int leaf = tid >> 4, c = tid & 15;
  int r = b * NN + 1024 + li0 + leaf;
  int e0 = s0a[r], e1 = s1a[r];
  floatx2 a0 = {0.f, 0.f}, a1 = {0.f, 0.f}, a2 = {0.f, 0.f}, a3 = {0.f, 0.f};
  for (int e = e0; e < e1; ++e) {
    int g = src[e] - b * NN;
    int lv = 31 - __clz(g);
    int2 t = wtab[lv];
    int idx = g - (t.y & 0xffff);
    uint4 u;
    if ((unsigned)idx < (unsigned)(t.y >> 16))
      u = *(const uint4*)&cache[(t.x + g) * CSTRIDE + c * 8];
    else
      u = *(const uint4*)&ah[(size_t)(b * NN + g) * AHS + hoff + c * 8];
    a0 += bfpair(u.x); a1 += bfpair(u.y); a2 += bfpair(u.z); a3 += bfpair(u.w);
  }
  float inv = 1.0f / (float)max(e1 - e0, 1);
  __attribute__((aligned(16))) unsigned short o[8];
  o[0] = f2bf(a0[0] * inv); o[1] = f2bf(a0[1] * inv);
  o[2] = f2bf(a1[0] * inv); o[3] = f2bf(a1[1] * inv);
  o[4] = f2bf(a2[0] * inv); o[5] = f2bf(a2[1] * inv);
  o[6] = f2bf(a3[0] * inv); o[7] = f2bf(a3[1] * inv);
  *(uint4*)&ah[(size_t)r * AHS + c * 8] = *(uint4*)&o[0];
}

// ---------------------------------------------------------------------------
// Finish agg for nodes 0..15 (tid<128); h at +hoff, closed-form deg.
__device__ __forceinline__ void ph_topfin(int b,
                                          const float* __restrict__ sroot,
                                          unsigned short* ah, int hoff) {
  int d = threadIdx.x;
  float S16[16], h16[16], Sv[16];
#pragma unroll
  for (int j = 0; j < 16; ++j) S16[j] = sroot[(size_t)(b * 16 + j) * DD + d];
#pragma unroll
  for (int j = 0; j < 16; ++j)
    h16[j] = bf2f(ah[(size_t)(b * NN + 16 + j) * AHS + hoff + d]);
#pragma unroll
  for (int k = 8; k < 16; ++k)
    Sv[k] = h16[2 * k - 16] + h16[2 * k - 15] + S16[2 * k - 16] + S16[2 * k - 15];
#pragma unroll
  for (int k = 7; k >= 1; --k)
    Sv[k] = bf2f(ah[(size_t)(b * NN + 2 * k) * AHS + hoff + d]) +
            bf2f(ah[(size_t)(b * NN + 2 * k + 1) * AHS + hoff + d]) +
            Sv[2 * k] + Sv[2 * k + 1];
#pragma unroll
  for (int k = 1; k < 16; ++k) {
    int dv = 31 - __clz(k);
    float inv = 1.0f / (float)((1 << (11 - dv)) - 2);
    ah[(size_t)(b * NN + k) * AHS + d] = f2bf(Sv[k] * inv);
  }
  ah[(size_t)(b * NN) * AHS + d] = f2bf(0.0f);
}

// ---------------------------------------------------------------------------
// x += [agg|h] @ [Wn;Wr] + bias (bf16 MFMA). 64 rows at rowbase (absolute).
// 8 waves = 4 m-tiles x 2 n-halves. h read at +hoff_in; optional fused LN+GELU
// writes h' at +256.
__device__ __forceinline__ void ph_gemm64(char* smemc, int rowbase,
                                          unsigned short* ah,
                                          const unsigned short* __restrict__ wfl,
                                          const float* __restrict__ bn,
                                          float* __restrict__ x, int hoff_in,
                                          const float* __restrict__ gamma,
                                          const float* __restrict__ beta,
                                          int write_h) {
  int wave = threadIdx.x >> 6, lane = threadIdx.x & 63;
  int mt = wave >> 1, nh = wave & 1;
  int r0 = rowbase + mt * 16;
  int m = lane & 15, q = lane >> 4;
  const unsigned short* arow = ah + (size_t)(r0 + m) * AHS + q * 8;
  const bf16x8* B = (const bf16x8*)wfl + lane;
  floatx4 acc[4];
#pragma unroll
  for (int ci = 0; ci < 4; ++ci) acc[ci] = (floatx4){0.f, 0.f, 0.f, 0.f};
#pragma unroll
  for (int kc = 0; kc < 8; ++kc) {
    int koff = (kc < 4) ? kc * 32 : hoff_in + (kc - 4) * 32;
    bf16x8 a0 = *(const bf16x8*)(arow + koff);
#pragma unroll
    for (int ci = 0; ci < 4; ++ci) {
      bf16x8 bb = B[(kc * 8 + nh * 4 + ci) * 64];
      acc[ci] = __builtin_amdgcn_mfma_f32_16x16x32_bf16(a0, bb, acc[ci], 0, 0, 0);
    }
  }
  float s1[4] = {0.f, 0.f, 0.f, 0.f}, s2[4] = {0.f, 0.f, 0.f, 0.f};
#pragma unroll
  for (int ci = 0; ci < 4; ++ci) {
    int col = (nh * 4 + ci) * 16 + m;
    float bias = bn[col];
#pragma unroll
    for (int r = 0; r < 4; ++r) {
      int row = r0 + q * 4 + r;
      float v = x[(size_t)row * DD + col] + acc[ci][r] + bias;
      x[(size_t)row * DD + col] = v;
      acc[ci][r] = v;
      s1[r] += v; s2[r] += v * v;
    }
  }
  if (write_h) {
#pragma unroll
    for (int r = 0; r < 4; ++r) {
      s1[r] += __shfl_xor(s1[r], 1); s2[r] += __shfl_xor(s2[r], 1);
      s1[r] += __shfl_xor(s1[r], 2); s2[r] += __shfl_xor(s2[r], 2);
      s1[r] += __shfl_xor(s1[r], 4); s2[r] += __shfl_xor(s2[r], 4);
      s1[r] += __shfl_xor(s1[r], 8); s2[r] += __shfl_xor(s2[r], 8);
    }
    float* red = (float*)smemc;     // 512 floats
    int ridx = (mt * 4 + q) * 4;
    if (m == 0) {
#pragma unroll
      for (int r = 0; r < 4; ++r) {
        red[(ridx + r) * 2 + nh] = s1[r];
        red[128 + (ridx + r) * 2 + nh] = s2[r];
      }
    }
    __syncthreads();
    float mu[4], rv[4];
#pragma unroll
    for (int r = 0; r < 4; ++r) {
      float t1 = red[(ridx + r) * 2] + red[(ridx + r) * 2 + 1];
      float t2 = red[128 + (ridx + r) * 2] + red[128 + (ridx + r) * 2 + 1];
      mu[r] = t1 * (1.0f / 128.0f);
      float var = t2 * (1.0f / 128.0f) - mu[r] * mu[r];
      rv[r] = rsqrtf(var + 1e-5f);
    }
#pragma unroll
    for (int ci = 0; ci < 4; ++ci) {
      int col = (nh * 4 + ci) * 16 + m;
      float gm = gamma[col], bt = beta[col];
#pragma unroll
      for (int r = 0; r < 4; ++r) {
        int row = r0 + q * 4 + r;
        float hh = gelu((acc[ci][r] - mu[r]) * rv[r] * gm + bt);
        ah[(size_t)row * AHS + 256 + col] = f2bf(hh);
      }
    }
  }
}

// ---------------------------------------------------------------------------
// Megakernel: 8 groups x 32 blocks (one batch each).
// Barriers: B0 (32), B1 (32), B2 (16 internal blocks only).
__global__ __launch_bounds__(NT, 1) void k_mega(
    const float* __restrict__ elements, const float* __restrict__ ln_gamma,
    const float* __restrict__ ln_beta, const float* __restrict__ w_nei,
    const float* __restrict__ b_nei, const float* __restrict__ w_root,
    const int* __restrict__ srcv, const int* __restrict__ dstv, int E,
    float* __restrict__ x, int* s0a, int* s1a, float* lvl4, float* sroot,
    unsigned short* wf, unsigned short* ah, int* bar) {
  __shared__ __align__(16) char smem[65536];
  int bid = blockIdx.x, tid = threadIdx.x;
  int b = bid >> 5, gb = bid & 31;
  int Eb = E >> 3;
  unsigned short* wfg = wf + (size_t)b * 65536;

  // ---- P0: tree+LN0+aggL0 (gb 0-15) || CSR (16-23) || repack (24-31) ----
  if (gb < 16) {
    ph_tree(smem, b, gb, elements, x, lvl4, ah, ln_gamma, ln_beta, sroot);
  } else if (gb < 24) {
    int base = b * Eb;
    for (int i = base + (gb - 16) * NT + tid; i < base + Eb; i += 8 * NT) {
      int dv = dstv[i];
      if (i == 0 || dstv[i - 1] != dv) s0a[dv] = i;
      if (i == base + Eb - 1 || dstv[i + 1] != dv) s1a[dv] = i + 1;
    }
  } else {
    int gi = (gb - 24) * NT + tid;   // 0..4095 frag units
    int lane = gi & 63, ct = (gi >> 6) & 7, kc = gi >> 9;
    int n = ct * 16 + (lane & 15);
    int k = kc * 32 + (lane >> 4) * 8;
    int kk = k & 127;
#pragma unroll
    for (int l = 0; l < 2; ++l) {
      const float* w = (k < 128) ? (w_nei + (size_t)l * DD * DD)
                                 : (w_root + (size_t)l * DD * DD);
      unsigned short* o = wfg + (size_t)l * 32768 + (size_t)gi * 8;
#pragma unroll
      for (int j = 0; j < 8; ++j) o[j] = f2bf(w[(size_t)(kk + j) * DD + n]);
    }
  }
  gbarN(bar, 0, 32);

  // ---- P1 (layer 0): internal GEMM tiles || leafagg + fused leaf GEMM ----
  if (gb < 16) {
    if (gb == 0) {
      ph_top(smem, b, lvl4, x, ah, ln_gamma, ln_beta);
      if (tid < 128) ph_topfin(b, sroot, ah, 128);
      __syncthreads();
    }
    ph_gemm64(smem, b * NN + gb * 64, ah, wfg, b_nei, x, 128,
              ln_gamma + DD, ln_beta + DD, 1);
  } else {
    int u0 = (gb - 16) * 2;
    ph_leafagg(smem, b, u0, srcv, s0a, s1a, ah, 128, lvl4, ln_gamma, ln_beta, 1);
    __syncthreads();
    ph_leafagg(smem, b, u0 + 1, srcv, s0a, s1a, ah, 128, lvl4, ln_gamma, ln_beta, 1);
    __syncthreads();
    ph_gemm64(smem, b * NN + 1024 + (gb - 16) * 64, ah, wfg, b_nei, x, 128,
              ln_gamma + DD, ln_beta + DD, 1);
  }
  gbarN(bar, 1, 32);

  // ---- P2 (layer 1) ----
  if (gb < 16) {
    ph_aggsub(smem, b, gb, ah, sroot);
    gbarN(bar, 2, 16);                 // internal blocks only
    if (gb == 0) {
      if (tid < 128) ph_topfin(b, sroot, ah, 256);
      __syncthreads();
    }
    ph_gemm64(smem, b * NN + gb * 64, ah, wfg + 32768, b_nei + DD, x, 256,
              ln_gamma, ln_beta, 0);
  } else {
    int u0 = (gb - 16) * 2;
    ph_leafagg(smem, b, u0, srcv, s0a, s1a, ah, 256, lvl4, ln_gamma, ln_beta, 0);
    __syncthreads();
    ph_leafagg(smem, b, u0 + 1, srcv, s0a, s1a, ah, 256, lvl4, ln_gamma, ln_beta, 0);
    __syncthreads();
    ph_gemm64(smem, b * NN + 1024 + (gb - 16) * 64, ah, wfg + 32768, b_nei + DD,
              x, 256, ln_gamma, ln_beta, 0);
  }
}

// ---------------------------------------------------------------------------
extern "C" void kernel_launch(void* const* d_in, const int* in_sizes, int n_in,
                              void* d_out, int out_size, void* d_ws, size_t ws_size,
                              hipStream_t stream) {
  const float* elements = (const float*)d_in[0];
  const float* ln_gamma = (const float*)d_in[1];
  const float* ln_beta  = (const float*)d_in[2];
  const float* w_nei    = (const float*)d_in[3];
  const float* b_nei    = (const float*)d_in[4];
  const float* w_root   = (const float*)d_in[5];
  const int*   edge     = (const int*)d_in[6];
  int E = in_sizes[6] / 2;
  const int* srcv = edge;
  const int* dstv = edge + E;
  float* x = (float*)d_out;

  char* ws = (char*)d_ws;
  int*            bar   = (int*)ws;                         // 8 KB used
  int*            s0    = (int*)(ws + 65536);               // 64 KB
  int*            s1    = (int*)(ws + 131072);              // 64 KB
  float*          lvl4  = (float*)(ws + 196608);            // 64 KB
  float*          sroot = (float*)(ws + 262144);            // 64 KB
  unsigned short* wf    = (unsigned short*)(ws + 327680);   // 1 MB (8 copies)
  unsigned short* ah    = (unsigned short*)(ws + 327680 + 1048576);  // 12.6 MB

  hipMemsetAsync(bar, 0, 8192, stream);
  k_mega<<<dim3(NB), dim3(NT), 0, stream>>>(
      elements, ln_gamma, ln_beta, w_nei, b_nei, w_root,
      srcv, dstv, E, x, s0, s1, lvl4, sroot, wf, ah, bar);
}

// Round 11
// 203.834 us; speedup vs baseline: 1.1203x; 1.1203x over previous
//
#include <hip/hip_runtime.h>
#include <hip/hip_bf16.h>

// Problem constants (fixed by the reference file)
#define LEAFN 1024
#define NN    2048            // nodes per batch incl. global node 0
#define BATCH 8
#define DD    128
#define ROWS  (BATCH*NN)      // 16384
#define AHS   384             // ah row stride: [agg(128) | hL0(128) | hL1(128)]
#define NB    256             // megakernel grid (1 block/CU)
#define NT    512             // threads per block (8 waves)

// ln(10000)/32
#define LOG1E4_OVER_32 0.28782313662425575f

typedef __bf16 bf16x8 __attribute__((ext_vector_type(8)));
typedef float  floatx4 __attribute__((ext_vector_type(4)));
typedef float  floatx2 __attribute__((ext_vector_type(2)));

__device__ __forceinline__ float bf2f(unsigned short u) {
  return __uint_as_float(((unsigned)u) << 16);
}
__device__ __forceinline__ unsigned short f2bf(float f) {
  unsigned u = __float_as_uint(f);
  u += 0x7FFFu + ((u >> 16) & 1u);          // round-to-nearest-even
  return (unsigned short)(u >> 16);
}
__device__ __forceinline__ float gelu(float v) {
  return 0.5f * v * (1.0f + erff(v * 0.70710678118f));
}
__device__ __forceinline__ floatx2 bfpair(unsigned u) {
  floatx2 r;
  r[0] = __uint_as_float(u << 16);
  r[1] = __uint_as_float(u & 0xffff0000u);
  return r;
}

__device__ __forceinline__ float enc_val(int node, int d) {
  float hp, vp;
  if (node == 0) { hp = -0.5f; vp = -1.0f; }
  else {
    int v = 31 - __clz(node);
    hp = (float)(node - (1 << v));
    vp = (float)v;
  }
  float pos = (d < 64) ? hp : vp;
  int i = ((d < 64) ? d : (d - 64)) >> 1;
  float inv = expf(-(float)i * LOG1E4_OVER_32);
  float ang = pos * inv;
  return (d & 1) ? cosf(ang) : sinf(ang);
}

// ---------------------------------------------------------------------------
// Per-group barrier over n participants (group g = bid>>5 = batch).
__device__ __forceinline__ void gbarN(int* bar, int slot, int n) {
  __syncthreads();
  if (threadIdx.x == 0) {
    int g = blockIdx.x >> 5;
    int* base = bar + (slot * 8 + g) * 64;
    __threadfence();                           // release (L2 wb)
    if (__hip_atomic_fetch_add(base, 1, __ATOMIC_RELAXED,
                               __HIP_MEMORY_SCOPE_AGENT) == n - 1)
      __hip_atomic_store(base + 32, 1, __ATOMIC_RELAXED,
                         __HIP_MEMORY_SCOPE_AGENT);
    while (!__hip_atomic_load(base + 32, __ATOMIC_RELAXED,
                              __HIP_MEMORY_SCOPE_AGENT))
      __builtin_amdgcn_s_sleep(2);
    __threadfence();                           // acquire (L2 inv)
  }
  __syncthreads();
}

// ---------------------------------------------------------------------------
// Tree build + layer-0 LN/GELU + in-LDS subtree sums (agg depth 4..9).
__device__ __forceinline__ void ph_tree(char* smemc, int b, int s,
                                        const float* __restrict__ elements,
                                        float* __restrict__ x,
                                        float* __restrict__ lvl4,
                                        unsigned short* __restrict__ ah,
                                        const float* __restrict__ gamma,
                                        const float* __restrict__ beta,
                                        float* __restrict__ sroot) {
  float* sm = (float*)smemc;                  // 127*128 floats = 63.5 KB
  int tid = threadIdx.x;
  const float4* src = (const float4*)(elements + (size_t)(b * LEAFN + s * 64) * DD);
  for (int i = tid; i < 2048; i += NT) {
    int f = i * 4;
    int j = f >> 7, d = f & 127;
    *(float4*)&sm[(63 + j) * DD + d] = src[i];
  }
  __syncthreads();
  for (int lv = 5; lv >= 0; --lv) {
    int nodes = 1 << lv;
    for (int idx = tid; idx < nodes * DD; idx += NT) {
      int k = nodes + (idx >> 7);
      int d = idx & 127;
      sm[(k - 1) * DD + d] = 0.5f * (sm[(2 * k - 1) * DD + d] + sm[(2 * k) * DD + d]);
    }
    __syncthreads();
  }
  if (tid < DD) lvl4[(b * 16 + s) * DD + tid] = sm[tid];
  __syncthreads();
  for (int idx = tid; idx < 127 * DD; idx += NT) {
    int k = (idx >> 7) + 1;
    int d = idx & 127;
    int lv = 31 - __clz(k);
    int g = ((16 + s) << lv) | (k - (1 << lv));
    float xv = sm[idx] + enc_val(g, d);
    x[((size_t)(b * NN + g)) * DD + d] = xv;
    sm[idx] = xv;
  }
  __syncthreads();
  // LN + GELU: h -> ah(+128) AND h overwrites sm (fp32)
  {
    int sub = tid & 7, dp = sub * 16;
    for (int rr = tid >> 3; rr < 127; rr += NT / 8) {
      float v[16], s1 = 0.f, s2 = 0.f;
#pragma unroll
      for (int j = 0; j < 16; ++j) { v[j] = sm[rr * DD + dp + j]; s1 += v[j]; s2 += v[j] * v[j]; }
      s1 += __shfl_xor(s1, 1); s2 += __shfl_xor(s2, 1);
      s1 += __shfl_xor(s1, 2); s2 += __shfl_xor(s2, 2);
      s1 += __shfl_xor(s1, 4); s2 += __shfl_xor(s2, 4);
      float mu = s1 * (1.0f / 128.0f);
      float var = s2 * (1.0f / 128.0f) - mu * mu;
      float rinv = rsqrtf(var + 1e-5f);
      int k = rr + 1, lv = 31 - __clz(k);
      int g = ((16 + s) << lv) | (k - (1 << lv));
      __attribute__((aligned(16))) unsigned short o[16];
#pragma unroll
      for (int j = 0; j < 16; ++j) {
        float hv = gelu((v[j] - mu) * rinv * gamma[dp + j] + beta[dp + j]);
        o[j] = f2bf(hv);
        sm[rr * DD + dp + j] = hv;
      }
      unsigned short* dst = &ah[(size_t)(b * NN + g) * AHS + 128 + dp];
      *(uint4*)&dst[0] = *(uint4*)&o[0];
      *(uint4*)&dst[8] = *(uint4*)&o[8];
    }
  }
  __syncthreads();
  // subtree-sum pyramid in LDS; agg (closed-form deg) -> ah(+0)
  for (int lv = 5; lv >= 0; --lv) {
    int nk = 1 << lv;
    float inv = 1.0f / (float)((1 << (7 - lv)) - 2);
    for (int idx = tid; idx < nk * DD; idx += NT) {
      int k = nk + (idx >> 7);
      int d = idx & 127;
      float S = sm[(2 * k - 1) * DD + d] + sm[(2 * k) * DD + d];
      if (lv < 5) S += sm[(4 * k - 1) * DD + d] + sm[(4 * k + 1) * DD + d];
      sm[(2 * k - 1) * DD + d] = S;
      int g = ((16 + s) << lv) | (k - nk);
      ah[(size_t)(b * NN + g) * AHS + d] = f2bf(S * inv);
    }
    __syncthreads();
  }
  if (tid < DD) sroot[(size_t)(b * 16 + s) * DD + tid] = sm[DD + tid];
}

// ---------------------------------------------------------------------------
// Top nodes 0..15: finish tree, write x and layer-0 h (tid<128).
__device__ __forceinline__ void ph_top(char* smemc, int b,
                                       const float* __restrict__ lvl4,
                                       float* __restrict__ x,
                                       unsigned short* __restrict__ ah,
                                       const float* __restrict__ gamma,
                                       const float* __restrict__ beta) {
  float (*xs)[DD] = (float(*)[DD])smemc;      // 8 KB
  int tid = threadIdx.x;
  if (tid < 128) {
    int d = tid;
    float v[16];
    for (int j = 0; j < 16; ++j) v[j] = lvl4[(b * 16 + j) * DD + d];
    for (int j = 0; j < 8; ++j) v[j] = 0.5f * (v[2 * j] + v[2 * j + 1]);
    for (int j = 0; j < 8; ++j) xs[8 + j][d] = v[j] + enc_val(8 + j, d);
    for (int j = 0; j < 4; ++j) v[j] = 0.5f * (v[2 * j] + v[2 * j + 1]);
    for (int j = 0; j < 4; ++j) xs[4 + j][d] = v[j] + enc_val(4 + j, d);
    for (int j = 0; j < 2; ++j) v[j] = 0.5f * (v[2 * j] + v[2 * j + 1]);
    for (int j = 0; j < 2; ++j) xs[2 + j][d] = v[j] + enc_val(2 + j, d);
    v[0] = 0.5f * (v[0] + v[1]);
    xs[1][d] = v[0] + enc_val(1, d);
    xs[0][d] = -1.0f + enc_val(0, d);
    for (int j = 0; j < 16; ++j) x[((size_t)(b * NN + j)) * DD + d] = xs[j][d];
  }
  __syncthreads();
  if (tid < 128) {
    int rr = tid >> 3, sub = tid & 7, dp = sub * 16;
    float w[16], s1 = 0.f, s2 = 0.f;
#pragma unroll
    for (int j = 0; j < 16; ++j) { w[j] = xs[rr][dp + j]; s1 += w[j]; s2 += w[j] * w[j]; }
    s1 += __shfl_xor(s1, 1); s2 += __shfl_xor(s2, 1);
    s1 += __shfl_xor(s1, 2); s2 += __shfl_xor(s2, 2);
    s1 += __shfl_xor(s1, 4); s2 += __shfl_xor(s2, 4);
    float mu = s1 * (1.0f / 128.0f);
    float var = s2 * (1.0f / 128.0f) - mu * mu;
    float rinv = rsqrtf(var + 1e-5f);
    __attribute__((aligned(16))) unsigned short o[16];
#pragma unroll
    for (int j = 0; j < 16; ++j)
      o[j] = f2bf(gelu((w[j] - mu) * rinv * gamma[dp + j] + beta[dp + j]));
    unsigned short* dst = &ah[(size_t)(b * NN + rr) * AHS + 128 + dp];
    *(uint4*)&dst[0] = *(uint4*)&o[0];
    *(uint4*)&dst[8] = *(uint4*)&o[8];
  }
  __syncthreads();
}

// ---------------------------------------------------------------------------
// Subtree sums for L1: reads h' from ah(+256), agg -> ah(+0), sroot.
__device__ __forceinline__ void ph_aggsub(char* smemc, int b, int s,
                                          unsigned short* ah,
                                          float* __restrict__ sroot) {
  floatx4 (*S)[32] = (floatx4(*)[32])smemc;   // 32 KB
  int tid = threadIdx.x;
  for (int idx = tid; idx < 32 * 32; idx += NT) {
    int k = 32 + (idx >> 5), q = idx & 31;
    int c = (16 + s) * 64 + (2 * k - 64);
    size_t a0 = (size_t)(b * NN + c) * AHS + 256 + q * 4;
    ushort4 u0 = *(const ushort4*)&ah[a0];
    ushort4 u1 = *(const ushort4*)&ah[a0 + AHS];
    floatx4 v;
    v[0] = bf2f(u0.x) + bf2f(u1.x);
    v[1] = bf2f(u0.y) + bf2f(u1.y);
    v[2] = bf2f(u0.z) + bf2f(u1.z);
    v[3] = bf2f(u0.w) + bf2f(u1.w);
    S[k][q] = v;
    int g = (16 + s) * 32 + (k - 32);
    int r = b * NN + g;
    ushort4 o;
    o.x = f2bf(v[0] * 0.5f); o.y = f2bf(v[1] * 0.5f);
    o.z = f2bf(v[2] * 0.5f); o.w = f2bf(v[3] * 0.5f);
    *(ushort4*)&ah[(size_t)r * AHS + q * 4] = o;
  }
  __syncthreads();
  for (int lv = 4; lv >= 0; --lv) {
    int nk = 1 << lv;
    float inv = 1.0f / (float)((1 << (7 - lv)) - 2);
    for (int idx = tid; idx < nk * 32; idx += NT) {
      int k = nk + (idx >> 5), q = idx & 31;
      int c = ((16 + s) << (lv + 1)) | (2 * k - 2 * nk);
      size_t a0 = (size_t)(b * NN + c) * AHS + 256 + q * 4;
      ushort4 u0 = *(const ushort4*)&ah[a0];
      ushort4 u1 = *(const ushort4*)&ah[a0 + AHS];
      floatx4 sc0 = S[2 * k][q], sc1 = S[2 * k + 1][q];
      floatx4 v;
      v[0] = bf2f(u0.x) + bf2f(u1.x) + sc0[0] + sc1[0];
      v[1] = bf2f(u0.y) + bf2f(u1.y) + sc0[1] + sc1[1];
      v[2] = bf2f(u0.z) + bf2f(u1.z) + sc0[2] + sc1[2];
      v[3] = bf2f(u0.w) + bf2f(u1.w) + sc0[3] + sc1[3];
      S[k][q] = v;
      int g = ((16 + s) << lv) | (k - nk);
      int r = b * NN + g;
      ushort4 o;
      o.x = f2bf(v[0] * inv); o.y = f2bf(v[1] * inv);
      o.z = f2bf(v[2] * inv); o.w = f2bf(v[3] * inv);
      *(ushort4*)&ah[(size_t)r * AHS + q * 4] = o;
    }
    __syncthreads();
  }
  for (int q = tid; q < 32; q += NT)
    ((floatx4*)sroot)[(size_t)(b * 16 + s) * 32 + q] = S[1][q];
}

// ---------------------------------------------------------------------------
// Leaf-row gather: per-level LDS window cache; h read at +hoff; agg -> +0.
// One 32-leaf unit (jb) per block, 512 thr = 32 leaves x 16 chunk-threads.
#define SLACK 10
#define CACHE_ROWS 220
#define CSTRIDE 136
__device__ __forceinline__ void ph_leafagg(char* smemc, int b, int jb,
                                           const int* __restrict__ src,
                                           const int* __restrict__ s0a,
                                           const int* __restrict__ s1a,
                                           unsigned short* ah, int hoff,
                                           const float* __restrict__ lvl4,
                                           const float* __restrict__ gamma,
                                           const float* __restrict__ beta,
                                           int l0patch) {
  unsigned short* cache = (unsigned short*)smemc;  // 59840 B
  int2* wtab = (int2*)(smemc + 60928);             // 11 entries
  int tid = threadIdx.x;
  int li0 = jb * 32;
  int g0 = 1024 + li0, g1 = g0 + 31;

  int lo[11], wd[11], off[11];
  int acc_off = 0;
  for (int cd = 10; cd >= 1; --cd) {
    int a0 = g0 >> (10 - cd), a1 = g1 >> (10 - cd);
    int l = a0 - SLACK, hgh = a1 + SLACK;
    int lvlo = 1 << cd, lvhi = (2 << cd) - 1;
    l = l < lvlo ? lvlo : l;
    hgh = hgh > lvhi ? lvhi : hgh;
    int w = hgh - l + 1;
    if (w < 0) w = 0;
    lo[cd] = l; wd[cd] = w; off[cd] = acc_off; acc_off += w;
  }
  if (tid >= 1 && tid <= 10) {
    int cd = tid;
    wtab[cd] = make_int2(off[cd] - lo[cd], lo[cd] | (wd[cd] << 16));
  }
  int cdmin = l0patch ? 4 : 1;
  for (int cd = 10; cd >= cdmin; --cd) {
    int w = wd[cd];
    for (int t = tid; t < w * 16; t += NT) {
      int row = t >> 4, seg = t & 15;
      *(uint4*)&cache[(off[cd] + row) * CSTRIDE + seg * 8] =
          *(const uint4*)&ah[(size_t)(b * NN + lo[cd] + row) * AHS + hoff + seg * 8];
    }
  }
  if (l0patch && tid < 112) {
    // h rows 2..15 computed locally from lvl4 (mean + enc + LN + GELU)
    int row = 2 + (tid >> 3), sub = tid & 7, dp = sub * 16;
    int dv = 31 - __clz(row);
    int cnt = 1 << (4 - dv);
    int l4r = (row << (4 - dv)) - 16;
    float v[16];
#pragma unroll
    for (int j = 0; j < 16; ++j) v[j] = 0.f;
    for (int c = 0; c < cnt; ++c) {
      const float* p = &lvl4[(size_t)(b * 16 + l4r + c) * DD + dp];
#pragma unroll
      for (int j = 0; j < 16; ++j) v[j] += p[j];
    }
    float sc = 1.0f / (float)cnt;
    float s1 = 0.f, s2 = 0.f;
#pragma unroll
    for (int j = 0; j < 16; ++j) {
      v[j] = v[j] * sc + enc_val(row, dp + j);
      s1 += v[j]; s2 += v[j] * v[j];
    }
    s1 += __shfl_xor(s1, 1); s2 += __shfl_xor(s2, 1);
    s1 += __shfl_xor(s1, 2); s2 += __shfl_xor(s2, 2);
    s1 += __shfl_xor(s1, 4); s2 += __shfl_xor(s2, 4);
    float mu = s1 * (1.0f / 128.0f);
    float var = s2 * (1.0f / 128.0f) - mu * mu;
    float rinv = rsqrtf(var + 1e-5f);
    __attribute__((aligned(16))) unsigned short o[16];
#pragma unroll
    for (int j = 0; j < 16; ++j)
      o[j] = f2bf(gelu((v[j] - mu) * rinv * gamma[dp + j] + beta[dp + j]));
    int cr = off[dv] + (row - lo[dv]);
    *(uint4*)&cache[cr * CSTRIDE + sub * 16] = *(uint4*)&o[0];
    *(uint4*)&cache[cr * CSTRIDE + sub * 16 + 8] = *(uint4*)&o[8];
  }
  __syncthreads();

  int leaf = tid >> 4, c = tid & 15;
  int r = b * NN + 1024 + li0 + leaf;
  int e0 = s0a[r], e1 = s1a[r];
  floatx2 a0 = {0.f, 0.f}, a1 = {0.f, 0.f}, a2 = {0.f, 0.f}, a3 = {0.f, 0.f};
  for (int e = e0; e < e1; ++e) {
    int g = src[e] - b * NN;
    int lv = 31 - __clz(g);
    int2 t = wtab[lv];
    int idx = g - (t.y & 0xffff);
    uint4 u;
    if ((unsigned)idx < (unsigned)(t.y >> 16))
      u = *(const uint4*)&cache[(t.x + g) * CSTRIDE + c * 8];
    else
      u = *(const uint4*)&ah[(size_t)(b * NN + g) * AHS + hoff + c * 8];
    a0 += bfpair(u.x); a1 += bfpair(u.y); a2 += bfpair(u.z); a3 += bfpair(u.w);
  }
  float inv = 1.0f / (float)max(e1 - e0, 1);
  __attribute__((aligned(16))) unsigned short o[8];
  o[0] = f2bf(a0[0] * inv); o[1] = f2bf(a0[1] * inv);
  o[2] = f2bf(a1[0] * inv); o[3] = f2bf(a1[1] * inv);
  o[4] = f2bf(a2[0] * inv); o[5] = f2bf(a2[1] * inv);
  o[6] = f2bf(a3[0] * inv); o[7] = f2bf(a3[1] * inv);
  *(uint4*)&ah[(size_t)r * AHS + c * 8] = *(uint4*)&o[0];
}

// ---------------------------------------------------------------------------
// Finish agg for nodes 0..15 (tid<128); h at +hoff, closed-form deg.
__device__ __forceinline__ void ph_topfin(int b,
                                          const float* __restrict__ sroot,
                                          unsigned short* ah, int hoff) {
  int d = threadIdx.x;
  float S16[16], h16[16], Sv[16];
#pragma unroll
  for (int j = 0; j < 16; ++j) S16[j] = sroot[(size_t)(b * 16 + j) * DD + d];
#pragma unroll
  for (int j = 0; j < 16; ++j)
    h16[j] = bf2f(ah[(size_t)(b * NN + 16 + j) * AHS + hoff + d]);
#pragma unroll
  for (int k = 8; k < 16; ++k)
    Sv[k] = h16[2 * k - 16] + h16[2 * k - 15] + S16[2 * k - 16] + S16[2 * k - 15];
#pragma unroll
  for (int k = 7; k >= 1; --k)
    Sv[k] = bf2f(ah[(size_t)(b * NN + 2 * k) * AHS + hoff + d]) +
            bf2f(ah[(size_t)(b * NN + 2 * k + 1) * AHS + hoff + d]) +
            Sv[2 * k] + Sv[2 * k + 1];
#pragma unroll
  for (int k = 1; k < 16; ++k) {
    int dv = 31 - __clz(k);
    float inv = 1.0f / (float)((1 << (11 - dv)) - 2);
    ah[(size_t)(b * NN + k) * AHS + d] = f2bf(Sv[k] * inv);
  }
  ah[(size_t)(b * NN) * AHS + d] = f2bf(0.0f);
}

// ---------------------------------------------------------------------------
// 32-row GEMM tile: out = [agg|h] @ [Wn;Wr] + bias (bf16 MFMA).
// 8 waves = 2 m-tiles x 4 n-quarters. first_layer=1: v = x0 + out + bias ->
// xc registers (x NOT written), fused LN+GELU -> h' at +256.
// first_layer=0: v = xc + out + bias -> final x write.
__device__ __forceinline__ void ph_gemm32(char* redc, int rowbase,
                                          unsigned short* ah,
                                          const unsigned short* __restrict__ wfl,
                                          const float* __restrict__ bn,
                                          float* __restrict__ x, int hoff_in,
                                          const float* __restrict__ gamma,
                                          const float* __restrict__ beta,
                                          float* xc, int first_layer) {
  int wave = threadIdx.x >> 6, lane = threadIdx.x & 63;
  int mt = wave >> 2, nq = wave & 3;
  int r0 = rowbase + mt * 16;
  int m = lane & 15, q = lane >> 4;
  const unsigned short* arow = ah + (size_t)(r0 + m) * AHS + q * 8;
  const bf16x8* B = (const bf16x8*)wfl + lane;
  floatx4 acc[2];
  acc[0] = (floatx4){0.f, 0.f, 0.f, 0.f};
  acc[1] = (floatx4){0.f, 0.f, 0.f, 0.f};
#pragma unroll
  for (int kc = 0; kc < 8; ++kc) {
    int koff = (kc < 4) ? kc * 32 : hoff_in + (kc - 4) * 32;
    bf16x8 a0 = *(const bf16x8*)(arow + koff);
#pragma unroll
    for (int ci = 0; ci < 2; ++ci) {
      bf16x8 bb = B[(kc * 8 + nq * 2 + ci) * 64];
      acc[ci] = __builtin_amdgcn_mfma_f32_16x16x32_bf16(a0, bb, acc[ci], 0, 0, 0);
    }
  }
  if (first_layer) {
    float s1[4] = {0.f, 0.f, 0.f, 0.f}, s2[4] = {0.f, 0.f, 0.f, 0.f};
#pragma unroll
    for (int ci = 0; ci < 2; ++ci) {
      int col = (nq * 2 + ci) * 16 + m;
      float bias = bn[col];
#pragma unroll
      for (int r = 0; r < 4; ++r) {
        int row = r0 + q * 4 + r;
        float v = x[(size_t)row * DD + col] + acc[ci][r] + bias;
        xc[ci * 4 + r] = v;
        s1[r] += v; s2[r] += v * v;
      }
    }
#pragma unroll
    for (int r = 0; r < 4; ++r) {
      s1[r] += __shfl_xor(s1[r], 1); s2[r] += __shfl_xor(s2[r], 1);
      s1[r] += __shfl_xor(s1[r], 2); s2[r] += __shfl_xor(s2[r], 2);
      s1[r] += __shfl_xor(s1[r], 4); s2[r] += __shfl_xor(s2[r], 4);
      s1[r] += __shfl_xor(s1[r], 8); s2[r] += __shfl_xor(s2[r], 8);
    }
    float* red = (float*)redc;                 // 256 floats
    int rl = mt * 16 + q * 4;
    __syncthreads();
    if (m == 0) {
#pragma unroll
      for (int r = 0; r < 4; ++r) {
        red[(rl + r) * 4 + nq] = s1[r];
        red[128 + (rl + r) * 4 + nq] = s2[r];
      }
    }
    __syncthreads();
    float mu[4], rv[4];
#pragma unroll
    for (int r = 0; r < 4; ++r) {
      float t1 = red[(rl + r) * 4] + red[(rl + r) * 4 + 1] +
                 red[(rl + r) * 4 + 2] + red[(rl + r) * 4 + 3];
      float t2 = red[128 + (rl + r) * 4] + red[128 + (rl + r) * 4 + 1] +
                 red[128 + (rl + r) * 4 + 2] + red[128 + (rl + r) * 4 + 3];
      mu[r] = t1 * (1.0f / 128.0f);
      float var = t2 * (1.0f / 128.0f) - mu[r] * mu[r];
      rv[r] = rsqrtf(var + 1e-5f);
    }
#pragma unroll
    for (int ci = 0; ci < 2; ++ci) {
      int col = (nq * 2 + ci) * 16 + m;
      float gm = gamma[col], bt = beta[col];
#pragma unroll
      for (int r = 0; r < 4; ++r) {
        int row = r0 + q * 4 + r;
        float hh = gelu((xc[ci * 4 + r] - mu[r]) * rv[r] * gm + bt);
        ah[(size_t)row * AHS + 256 + col] = f2bf(hh);
      }
    }
  } else {
#pragma unroll
    for (int ci = 0; ci < 2; ++ci) {
      int col = (nq * 2 + ci) * 16 + m;
      float bias = bn[col];
#pragma unroll
      for (int r = 0; r < 4; ++r) {
        int row = r0 + q * 4 + r;
        x[(size_t)row * DD + col] = xc[ci * 4 + r] + acc[ci][r] + bias;
      }
    }
  }
}

// ---------------------------------------------------------------------------
// Megakernel: 8 groups x 32 blocks (one batch each). 3 all-32 group barriers.
// Block gb owns: leaf unit gb (32 leaves = rows 1024+gb*32) AND internal rows
// gb*32..gb*32+31, across BOTH layers (x carried in registers between layers).
__global__ __launch_bounds__(NT, 1) void k_mega(
    const float* __restrict__ elements, const float* __restrict__ ln_gamma,
    const float* __restrict__ ln_beta, const float* __restrict__ w_nei,
    const float* __restrict__ b_nei, const float* __restrict__ w_root,
    const int* __restrict__ srcv, const int* __restrict__ dstv, int E,
    float* __restrict__ x, int* s0a, int* s1a, float* lvl4, float* sroot,
    unsigned short* wf, unsigned short* ah, int* bar) {
  __shared__ __align__(16) char smem[65536];
  int bid = blockIdx.x, tid = threadIdx.x;
  int b = bid >> 5, gb = bid & 31;
  int Eb = E >> 3;
  unsigned short* wfg = wf + (size_t)b * 65536;

  // ---- P0: tree+LN0+aggL0 (gb 0-15) || CSR (16-23) || repack (24-31) ----
  if (gb < 16) {
    ph_tree(smem, b, gb, elements, x, lvl4, ah, ln_gamma, ln_beta, sroot);
  } else if (gb < 24) {
    int base = b * Eb;
    for (int i = base + (gb - 16) * NT + tid; i < base + Eb; i += 8 * NT) {
      int dv = dstv[i];
      if (i == 0 || dstv[i - 1] != dv) s0a[dv] = i;
      if (i == base + Eb - 1 || dstv[i + 1] != dv) s1a[dv] = i + 1;
    }
  } else {
    int gi = (gb - 24) * NT + tid;   // 0..4095 frag units
    int lane = gi & 63, ct = (gi >> 6) & 7, kc = gi >> 9;
    int n = ct * 16 + (lane & 15);
    int k = kc * 32 + (lane >> 4) * 8;
    int kk = k & 127;
#pragma unroll
    for (int l = 0; l < 2; ++l) {
      const float* w = (k < 128) ? (w_nei + (size_t)l * DD * DD)
                                 : (w_root + (size_t)l * DD * DD);
      unsigned short* o = wfg + (size_t)l * 32768 + (size_t)gi * 8;
#pragma unroll
      for (int j = 0; j < 8; ++j) o[j] = f2bf(w[(size_t)(kk + j) * DD + n]);
    }
  }
  gbarN(bar, 0, 32);

  float xcl[8], xci[8];   // register-carried x (leaf tile, internal tile)

  // ---- P1 (layer 0) ----
  if (gb == 0) {
    ph_top(smem, b, lvl4, x, ah, ln_gamma, ln_beta);
    if (tid < 128) ph_topfin(b, sroot, ah, 128);
    __syncthreads();
  }
  ph_leafagg(smem, b, gb, srcv, s0a, s1a, ah, 128, lvl4, ln_gamma, ln_beta, 1);
  __syncthreads();
  ph_gemm32(smem + 61440, b * NN + 1024 + gb * 32, ah, wfg, b_nei, x, 128,
            ln_gamma + DD, ln_beta + DD, xcl, 1);
  ph_gemm32(smem + 61440, b * NN + gb * 32, ah, wfg, b_nei, x, 128,
            ln_gamma + DD, ln_beta + DD, xci, 1);
  gbarN(bar, 1, 32);

  // ---- P2 (layer 1) ----
  if (gb < 16) {
    ph_aggsub(smem, b, gb, ah, sroot);
    __syncthreads();
  }
  ph_leafagg(smem, b, gb, srcv, s0a, s1a, ah, 256, lvl4, ln_gamma, ln_beta, 0);
  __syncthreads();
  ph_gemm32(smem + 61440, b * NN + 1024 + gb * 32, ah, wfg + 32768, b_nei + DD,
            x, 256, ln_gamma, ln_beta, xcl, 0);
  gbarN(bar, 2, 32);
  if (gb == 0) {
    if (tid < 128) ph_topfin(b, sroot, ah, 256);
    __syncthreads();
  }
  ph_gemm32(smem + 61440, b * NN + gb * 32, ah, wfg + 32768, b_nei + DD,
            x, 256, ln_gamma, ln_beta, xci, 0);
}

// ---------------------------------------------------------------------------
extern "C" void kernel_launch(void* const* d_in, const int* in_sizes, int n_in,
                              void* d_out, int out_size, void* d_ws, size_t ws_size,
                              hipStream_t stream) {
  const float* elements = (const float*)d_in[0];
  const float* ln_gamma = (const float*)d_in[1];
  const float* ln_beta  = (const float*)d_in[2];
  const float* w_nei    = (const float*)d_in[3];
  const float* b_nei    = (const float*)d_in[4];
  const float* w_root   = (const float*)d_in[5];
  const int*   edge     = (const int*)d_in[6];
  int E = in_sizes[6] / 2;
  const int* srcv = edge;
  const int* dstv = edge + E;
  float* x = (float*)d_out;

  char* ws = (char*)d_ws;
  int*            bar   = (int*)ws;                         // 8 KB used
  int*            s0    = (int*)(ws + 65536);               // 64 KB
  int*            s1    = (int*)(ws + 131072);              // 64 KB
  float*          lvl4  = (float*)(ws + 196608);            // 64 KB
  float*          sroot = (float*)(ws + 262144);            // 64 KB
  unsigned short* wf    = (unsigned short*)(ws + 327680);   // 1 MB (8 copies)
  unsigned short* ah    = (unsigned short*)(ws + 327680 + 1048576);  // 12.6 MB

  hipMemsetAsync(bar, 0, 8192, stream);
  k_mega<<<dim3(NB), dim3(NT), 0, stream>>>(
      elements, ln_gamma, ln_beta, w_nei, b_nei, w_root,
      srcv, dstv, E, x, s0, s1, lvl4, sroot, wf, ah, bar);
}

// Round 12
// 203.639 us; speedup vs baseline: 1.1214x; 1.0010x over previous
//
#include <hip/hip_runtime.h>
#include <hip/hip_bf16.h>

// Problem constants (fixed by the reference file)
#define LEAFN 1024
#define NN    2048            // nodes per batch incl. global node 0
#define BATCH 8
#define DD    128
#define ROWS  (BATCH*NN)      // 16384
#define AHS   384             // ah row stride: [agg(128) | hL0(128) | hL1(128)]
#define NB    256             // megakernel grid (1 block/CU)
#define NT    512             // threads per block (8 waves)

// ln(10000)/32
#define LOG1E4_OVER_32 0.28782313662425575f

typedef __bf16 bf16x8 __attribute__((ext_vector_type(8)));
typedef float  floatx4 __attribute__((ext_vector_type(4)));
typedef float  floatx2 __attribute__((ext_vector_type(2)));

__device__ __forceinline__ float bf2f(unsigned short u) {
  return __uint_as_float(((unsigned)u) << 16);
}
__device__ __forceinline__ unsigned short f2bf(float f) {
  unsigned u = __float_as_uint(f);
  u += 0x7FFFu + ((u >> 16) & 1u);          // round-to-nearest-even
  return (unsigned short)(u >> 16);
}
__device__ __forceinline__ float gelu(float v) {
  return 0.5f * v * (1.0f + erff(v * 0.70710678118f));
}
__device__ __forceinline__ floatx2 bfpair(unsigned u) {
  floatx2 r;
  r[0] = __uint_as_float(u << 16);
  r[1] = __uint_as_float(u & 0xffff0000u);
  return r;
}

__device__ __forceinline__ float enc_val(int node, int d) {
  float hp, vp;
  if (node == 0) { hp = -0.5f; vp = -1.0f; }
  else {
    int v = 31 - __clz(node);
    hp = (float)(node - (1 << v));
    vp = (float)v;
  }
  float pos = (d < 64) ? hp : vp;
  int i = ((d < 64) ? d : (d - 64)) >> 1;
  float inv = expf(-(float)i * LOG1E4_OVER_32);
  float ang = pos * inv;
  return (d & 1) ? cosf(ang) : sinf(ang);
}

// ---------------------------------------------------------------------------
// Per-group barrier over 32 blocks (group g = bid>>5 = batch). Slots 0,1.
__device__ __forceinline__ void gbarN(int* bar, int slot) {
  __syncthreads();
  if (threadIdx.x == 0) {
    int g = blockIdx.x >> 5;
    int* base = bar + (slot * 8 + g) * 64;
    __threadfence();                           // release (L2 wb)
    if (__hip_atomic_fetch_add(base, 1, __ATOMIC_RELAXED,
                               __HIP_MEMORY_SCOPE_AGENT) == 31)
      __hip_atomic_store(base + 32, 1, __ATOMIC_RELAXED,
                         __HIP_MEMORY_SCOPE_AGENT);
    while (!__hip_atomic_load(base + 32, __ATOMIC_RELAXED,
                              __HIP_MEMORY_SCOPE_AGENT))
      __builtin_amdgcn_s_sleep(2);
    __threadfence();                           // acquire (L2 inv)
  }
  __syncthreads();
}

// ---------------------------------------------------------------------------
// Tree build + layer-0 LN/GELU + in-LDS subtree sums; stashes x0 of the 64
// internal-gemm tile rows (subtree heap order + dup) into xci registers.
__device__ __forceinline__ void ph_tree(char* smemc, int b, int s,
                                        const float* __restrict__ elements,
                                        float* __restrict__ x,
                                        float* __restrict__ lvl4,
                                        unsigned short* __restrict__ ah,
                                        const float* __restrict__ gamma,
                                        const float* __restrict__ beta,
                                        float* __restrict__ sroot,
                                        float* xci) {
  float* sm = (float*)smemc;                  // 127*128 floats = 63.5 KB
  int tid = threadIdx.x;
  const float4* src = (const float4*)(elements + (size_t)(b * LEAFN + s * 64) * DD);
  for (int i = tid; i < 2048; i += NT) {
    int f = i * 4;
    int j = f >> 7, d = f & 127;
    *(float4*)&sm[(63 + j) * DD + d] = src[i];
  }
  __syncthreads();
  for (int lv = 5; lv >= 0; --lv) {
    int nodes = 1 << lv;
    for (int idx = tid; idx < nodes * DD; idx += NT) {
      int k = nodes + (idx >> 7);
      int d = idx & 127;
      sm[(k - 1) * DD + d] = 0.5f * (sm[(2 * k - 1) * DD + d] + sm[(2 * k) * DD + d]);
    }
    __syncthreads();
  }
  if (tid < DD) lvl4[(b * 16 + s) * DD + tid] = sm[tid];
  __syncthreads();
  // x = feat + enc; keep in sm; write global x ONLY for leaf rows (k>=64)
  for (int idx = tid; idx < 127 * DD; idx += NT) {
    int k = (idx >> 7) + 1;
    int d = idx & 127;
    int lv = 31 - __clz(k);
    int g = ((16 + s) << lv) | (k - (1 << lv));
    float xv = sm[idx] + enc_val(g, d);
    if (k >= 64) x[((size_t)(b * NN + g)) * DD + d] = xv;
    sm[idx] = xv;
  }
  __syncthreads();
  // stash x0 for this block's internal gemm tiles (2 x 32 rows, dup t=63->k=1)
  {
    int wave = tid >> 6, lane = tid & 63;
    int mt = wave >> 2, nq = wave & 3;
    int m = lane & 15, q = lane >> 4;
#pragma unroll
    for (int c = 0; c < 2; ++c)
#pragma unroll
      for (int ci = 0; ci < 2; ++ci)
#pragma unroll
        for (int r = 0; r < 4; ++r) {
          int t = c * 32 + mt * 16 + q * 4 + r;
          int k = (t == 63) ? 1 : t + 1;
          int d = (nq * 2 + ci) * 16 + m;
          xci[c * 8 + ci * 4 + r] = sm[(k - 1) * DD + d];
        }
  }
  __syncthreads();
  // LN + GELU: h -> ah(+128) AND h overwrites sm (fp32)
  {
    int sub = tid & 7, dp = sub * 16;
    for (int rr = tid >> 3; rr < 127; rr += NT / 8) {
      float v[16], s1 = 0.f, s2 = 0.f;
#pragma unroll
      for (int j = 0; j < 16; ++j) { v[j] = sm[rr * DD + dp + j]; s1 += v[j]; s2 += v[j] * v[j]; }
      s1 += __shfl_xor(s1, 1); s2 += __shfl_xor(s2, 1);
      s1 += __shfl_xor(s1, 2); s2 += __shfl_xor(s2, 2);
      s1 += __shfl_xor(s1, 4); s2 += __shfl_xor(s2, 4);
      float mu = s1 * (1.0f / 128.0f);
      float var = s2 * (1.0f / 128.0f) - mu * mu;
      float rinv = rsqrtf(var + 1e-5f);
      int k = rr + 1, lv = 31 - __clz(k);
      int g = ((16 + s) << lv) | (k - (1 << lv));
      __attribute__((aligned(16))) unsigned short o[16];
#pragma unroll
      for (int j = 0; j < 16; ++j) {
        float hv = gelu((v[j] - mu) * rinv * gamma[dp + j] + beta[dp + j]);
        o[j] = f2bf(hv);
        sm[rr * DD + dp + j] = hv;
      }
      unsigned short* dst = &ah[(size_t)(b * NN + g) * AHS + 128 + dp];
      *(uint4*)&dst[0] = *(uint4*)&o[0];
      *(uint4*)&dst[8] = *(uint4*)&o[8];
    }
  }
  __syncthreads();
  // subtree-sum pyramid in LDS; agg (closed-form deg) -> ah(+0)
  for (int lv = 5; lv >= 0; --lv) {
    int nk = 1 << lv;
    float inv = 1.0f / (float)((1 << (7 - lv)) - 2);
    for (int idx = tid; idx < nk * DD; idx += NT) {
      int k = nk + (idx >> 7);
      int d = idx & 127;
      float S = sm[(2 * k - 1) * DD + d] + sm[(2 * k) * DD + d];
      if (lv < 5) S += sm[(4 * k - 1) * DD + d] + sm[(4 * k + 1) * DD + d];
      sm[(2 * k - 1) * DD + d] = S;
      int g = ((16 + s) << lv) | (k - nk);
      ah[(size_t)(b * NN + g) * AHS + d] = f2bf(S * inv);
    }
    __syncthreads();
  }
  if (tid < DD) sroot[(size_t)(b * 16 + s) * DD + tid] = sm[DD + tid];
}

// ---------------------------------------------------------------------------
// Top nodes 0..15: x0 into LDS xs (no global write), layer-0 h -> ah.
__device__ __forceinline__ void ph_top(char* smemc, int b,
                                       const float* __restrict__ lvl4,
                                       unsigned short* __restrict__ ah,
                                       const float* __restrict__ gamma,
                                       const float* __restrict__ beta) {
  float (*xs)[DD] = (float(*)[DD])smemc;      // 8 KB
  int tid = threadIdx.x;
  if (tid < 128) {
    int d = tid;
    float v[16];
    for (int j = 0; j < 16; ++j) v[j] = lvl4[(b * 16 + j) * DD + d];
    for (int j = 0; j < 8; ++j) v[j] = 0.5f * (v[2 * j] + v[2 * j + 1]);
    for (int j = 0; j < 8; ++j) xs[8 + j][d] = v[j] + enc_val(8 + j, d);
    for (int j = 0; j < 4; ++j) v[j] = 0.5f * (v[2 * j] + v[2 * j + 1]);
    for (int j = 0; j < 4; ++j) xs[4 + j][d] = v[j] + enc_val(4 + j, d);
    for (int j = 0; j < 2; ++j) v[j] = 0.5f * (v[2 * j] + v[2 * j + 1]);
    for (int j = 0; j < 2; ++j) xs[2 + j][d] = v[j] + enc_val(2 + j, d);
    v[0] = 0.5f * (v[0] + v[1]);
    xs[1][d] = v[0] + enc_val(1, d);
    xs[0][d] = -1.0f + enc_val(0, d);
  }
  __syncthreads();
  if (tid < 128) {
    int rr = tid >> 3, sub = tid & 7, dp = sub * 16;
    float w[16], s1 = 0.f, s2 = 0.f;
#pragma unroll
    for (int j = 0; j < 16; ++j) { w[j] = xs[rr][dp + j]; s1 += w[j]; s2 += w[j] * w[j]; }
    s1 += __shfl_xor(s1, 1); s2 += __shfl_xor(s2, 1);
    s1 += __shfl_xor(s1, 2); s2 += __shfl_xor(s2, 2);
    s1 += __shfl_xor(s1, 4); s2 += __shfl_xor(s2, 4);
    float mu = s1 * (1.0f / 128.0f);
    float var = s2 * (1.0f / 128.0f) - mu * mu;
    float rinv = rsqrtf(var + 1e-5f);
    __attribute__((aligned(16))) unsigned short o[16];
#pragma unroll
    for (int j = 0; j < 16; ++j)
      o[j] = f2bf(gelu((w[j] - mu) * rinv * gamma[dp + j] + beta[dp + j]));
    unsigned short* dst = &ah[(size_t)(b * NN + rr) * AHS + 128 + dp];
    *(uint4*)&dst[0] = *(uint4*)&o[0];
    *(uint4*)&dst[8] = *(uint4*)&o[8];
  }
  __syncthreads();
}

// ---------------------------------------------------------------------------
// Subtree sums for L1: reads h' from ah(+256), agg -> ah(+0), sroot.
__device__ __forceinline__ void ph_aggsub(char* smemc, int b, int s,
                                          unsigned short* ah,
                                          float* __restrict__ sroot) {
  floatx4 (*S)[32] = (floatx4(*)[32])smemc;   // 32 KB
  int tid = threadIdx.x;
  for (int idx = tid; idx < 32 * 32; idx += NT) {
    int k = 32 + (idx >> 5), q = idx & 31;
    int c = (16 + s) * 64 + (2 * k - 64);
    size_t a0 = (size_t)(b * NN + c) * AHS + 256 + q * 4;
    ushort4 u0 = *(const ushort4*)&ah[a0];
    ushort4 u1 = *(const ushort4*)&ah[a0 + AHS];
    floatx4 v;
    v[0] = bf2f(u0.x) + bf2f(u1.x);
    v[1] = bf2f(u0.y) + bf2f(u1.y);
    v[2] = bf2f(u0.z) + bf2f(u1.z);
    v[3] = bf2f(u0.w) + bf2f(u1.w);
    S[k][q] = v;
    int g = (16 + s) * 32 + (k - 32);
    int r = b * NN + g;
    ushort4 o;
    o.x = f2bf(v[0] * 0.5f); o.y = f2bf(v[1] * 0.5f);
    o.z = f2bf(v[2] * 0.5f); o.w = f2bf(v[3] * 0.5f);
    *(ushort4*)&ah[(size_t)r * AHS + q * 4] = o;
  }
  __syncthreads();
  for (int lv = 4; lv >= 0; --lv) {
    int nk = 1 << lv;
    float inv = 1.0f / (float)((1 << (7 - lv)) - 2);
    for (int idx = tid; idx < nk * 32; idx += NT) {
      int k = nk + (idx >> 5), q = idx & 31;
      int c = ((16 + s) << (lv + 1)) | (2 * k - 2 * nk);
      size_t a0 = (size_t)(b * NN + c) * AHS + 256 + q * 4;
      ushort4 u0 = *(const ushort4*)&ah[a0];
      ushort4 u1 = *(const ushort4*)&ah[a0 + AHS];
      floatx4 sc0 = S[2 * k][q], sc1 = S[2 * k + 1][q];
      floatx4 v;
      v[0] = bf2f(u0.x) + bf2f(u1.x) + sc0[0] + sc1[0];
      v[1] = bf2f(u0.y) + bf2f(u1.y) + sc0[1] + sc1[1];
      v[2] = bf2f(u0.z) + bf2f(u1.z) + sc0[2] + sc1[2];
      v[3] = bf2f(u0.w) + bf2f(u1.w) + sc0[3] + sc1[3];
      S[k][q] = v;
      int g = ((16 + s) << lv) | (k - nk);
      int r = b * NN + g;
      ushort4 o;
      o.x = f2bf(v[0] * inv); o.y = f2bf(v[1] * inv);
      o.z = f2bf(v[2] * inv); o.w = f2bf(v[3] * inv);
      *(ushort4*)&ah[(size_t)r * AHS + q * 4] = o;
    }
    __syncthreads();
  }
  for (int q = tid; q < 32; q += NT)
    ((floatx4*)sroot)[(size_t)(b * 16 + s) * 32 + q] = S[1][q];
}

// ---------------------------------------------------------------------------
// Leaf-row gather: per-level LDS window cache; h read at +hoff; agg -> +0.
#define SLACK 10
#define CACHE_ROWS 220
#define CSTRIDE 136
__device__ __forceinline__ void ph_leafagg(char* smemc, int b, int jb,
                                           const int* __restrict__ src,
                                           const int* __restrict__ s0a,
                                           const int* __restrict__ s1a,
                                           unsigned short* ah, int hoff,
                                           const float* __restrict__ lvl4,
                                           const float* __restrict__ gamma,
                                           const float* __restrict__ beta,
                                           int l0patch) {
  unsigned short* cache = (unsigned short*)smemc;  // 59840 B
  int2* wtab = (int2*)(smemc + 60928);             // 11 entries
  int tid = threadIdx.x;
  int li0 = jb * 32;
  int g0 = 1024 + li0, g1 = g0 + 31;

  int lo[11], wd[11], off[11];
  int acc_off = 0;
  for (int cd = 10; cd >= 1; --cd) {
    int a0 = g0 >> (10 - cd), a1 = g1 >> (10 - cd);
    int l = a0 - SLACK, hgh = a1 + SLACK;
    int lvlo = 1 << cd, lvhi = (2 << cd) - 1;
    l = l < lvlo ? lvlo : l;
    hgh = hgh > lvhi ? lvhi : hgh;
    int w = hgh - l + 1;
    if (w < 0) w = 0;
    lo[cd] = l; wd[cd] = w; off[cd] = acc_off; acc_off += w;
  }
  if (tid >= 1 && tid <= 10) {
    int cd = tid;
    wtab[cd] = make_int2(off[cd] - lo[cd], lo[cd] | (wd[cd] << 16));
  }
  int cdmin = l0patch ? 4 : 1;
  for (int cd = 10; cd >= cdmin; --cd) {
    int w = wd[cd];
    for (int t = tid; t < w * 16; t += NT) {
      int row = t >> 4, seg = t & 15;
      *(uint4*)&cache[(off[cd] + row) * CSTRIDE + seg * 8] =
          *(const uint4*)&ah[(size_t)(b * NN + lo[cd] + row) * AHS + hoff + seg * 8];
    }
  }
  if (l0patch && tid < 112) {
    // h rows 2..15 computed locally from lvl4 (mean + enc + LN + GELU)
    int row = 2 + (tid >> 3), sub = tid & 7, dp = sub * 16;
    int dv = 31 - __clz(row);
    int cnt = 1 << (4 - dv);
    int l4r = (row << (4 - dv)) - 16;
    float v[16];
#pragma unroll
    for (int j = 0; j < 16; ++j) v[j] = 0.f;
    for (int c = 0; c < cnt; ++c) {
      const float* p = &lvl4[(size_t)(b * 16 + l4r + c) * DD + dp];
#pragma unroll
      for (int j = 0; j < 16; ++j) v[j] += p[j];
    }
    float sc = 1.0f / (float)cnt;
    float s1 = 0.f, s2 = 0.f;
#pragma unroll
    for (int j = 0; j < 16; ++j) {
      v[j] = v[j] * sc + enc_val(row, dp + j);
      s1 += v[j]; s2 += v[j] * v[j];
    }
    s1 += __shfl_xor(s1, 1); s2 += __shfl_xor(s2, 1);
    s1 += __shfl_xor(s1, 2); s2 += __shfl_xor(s2, 2);
    s1 += __shfl_xor(s1, 4); s2 += __shfl_xor(s2, 4);
    float mu = s1 * (1.0f / 128.0f);
    float var = s2 * (1.0f / 128.0f) - mu * mu;
    float rinv = rsqrtf(var + 1e-5f);
    __attribute__((aligned(16))) unsigned short o[16];
#pragma unroll
    for (int j = 0; j < 16; ++j)
      o[j] = f2bf(gelu((v[j] - mu) * rinv * gamma[dp + j] + beta[dp + j]));
    int cr = off[dv] + (row - lo[dv]);
    *(uint4*)&cache[cr * CSTRIDE + sub * 16] = *(uint4*)&o[0];
    *(uint4*)&cache[cr * CSTRIDE + sub * 16 + 8] = *(uint4*)&o[8];
  }
  __syncthreads();

  int leaf = tid >> 4, c = tid & 15;
  int r = b * NN + 1024 + li0 + leaf;
  int e0 = s0a[r], e1 = s1a[r];
  floatx2 a0 = {0.f, 0.f}, a1 = {0.f, 0.f}, a2 = {0.f, 0.f}, a3 = {0.f, 0.f};
  for (int e = e0; e < e1; ++e) {
    int g = src[e] - b * NN;
    int lv = 31 - __clz(g);
    int2 t = wtab[lv];
    int idx = g - (t.y & 0xffff);
    uint4 u;
    if ((unsigned)idx < (unsigned)(t.y >> 16))
      u = *(const uint4*)&cache[(t.x + g) * CSTRIDE + c * 8];
    else
      u = *(const uint4*)&ah[(size_t)(b * NN + g) * AHS + hoff + c * 8];
    a0 += bfpair(u.x); a1 += bfpair(u.y); a2 += bfpair(u.z); a3 += bfpair(u.w);
  }
  float inv = 1.0f / (float)max(e1 - e0, 1);
  __attribute__((aligned(16))) unsigned short o[8];
  o[0] = f2bf(a0[0] * inv); o[1] = f2bf(a0[1] * inv);
  o[2] = f2bf(a1[0] * inv); o[3] = f2bf(a1[1] * inv);
  o[4] = f2bf(a2[0] * inv); o[5] = f2bf(a2[1] * inv);
  o[6] = f2bf(a3[0] * inv); o[7] = f2bf(a3[1] * inv);
  *(uint4*)&ah[(size_t)r * AHS + c * 8] = *(uint4*)&o[0];
}

// ---------------------------------------------------------------------------
// Finish agg for nodes 0..15 (tid<128); h at +hoff, closed-form deg.
__device__ __forceinline__ void ph_topfin(int b,
                                          const float* __restrict__ sroot,
                                          unsigned short* ah, int hoff) {
  int d = threadIdx.x;
  float S16[16], h16[16], Sv[16];
#pragma unroll
  for (int j = 0; j < 16; ++j) S16[j] = sroot[(size_t)(b * 16 + j) * DD + d];
#pragma unroll
  for (int j = 0; j < 16; ++j)
    h16[j] = bf2f(ah[(size_t)(b * NN + 16 + j) * AHS + hoff + d]);
#pragma unroll
  for (int k = 8; k < 16; ++k)
    Sv[k] = h16[2 * k - 16] + h16[2 * k - 15] + S16[2 * k - 16] + S16[2 * k - 15];
#pragma unroll
  for (int k = 7; k >= 1; --k)
    Sv[k] = bf2f(ah[(size_t)(b * NN + 2 * k) * AHS + hoff + d]) +
            bf2f(ah[(size_t)(b * NN + 2 * k + 1) * AHS + hoff + d]) +
            Sv[2 * k] + Sv[2 * k + 1];
#pragma unroll
  for (int k = 1; k < 16; ++k) {
    int dv = 31 - __clz(k);
    float inv = 1.0f / (float)((1 << (11 - dv)) - 2);
    ah[(size_t)(b * NN + k) * AHS + d] = f2bf(Sv[k] * inv);
  }
  ah[(size_t)(b * NN) * AHS + d] = f2bf(0.0f);
}

// ---------------------------------------------------------------------------
// 32-row leaf GEMM tile (contiguous rows at rowbase). first_layer=1:
// v = x0(global read) + out + bias -> xc regs + LN/GELU h'->+256.
// first_layer=0: x = xc + out + bias (final write).
__device__ __forceinline__ void ph_gemm32(char* redc, int rowbase,
                                          unsigned short* ah,
                                          const unsigned short* __restrict__ wfl,
                                          const float* __restrict__ bn,
                                          float* __restrict__ x, int hoff_in,
                                          const float* __restrict__ gamma,
                                          const float* __restrict__ beta,
                                          float* xc, int first_layer) {
  int wave = threadIdx.x >> 6, lane = threadIdx.x & 63;
  int mt = wave >> 2, nq = wave & 3;
  int r0 = rowbase + mt * 16;
  int m = lane & 15, q = lane >> 4;
  const unsigned short* arow = ah + (size_t)(r0 + m) * AHS + q * 8;
  const bf16x8* B = (const bf16x8*)wfl + lane;
  floatx4 acc[2];
  acc[0] = (floatx4){0.f, 0.f, 0.f, 0.f};
  acc[1] = (floatx4){0.f, 0.f, 0.f, 0.f};
#pragma unroll
  for (int kc = 0; kc < 8; ++kc) {
    int koff = (kc < 4) ? kc * 32 : hoff_in + (kc - 4) * 32;
    bf16x8 a0 = *(const bf16x8*)(arow + koff);
#pragma unroll
    for (int ci = 0; ci < 2; ++ci) {
      bf16x8 bb = B[(kc * 8 + nq * 2 + ci) * 64];
      acc[ci] = __builtin_amdgcn_mfma_f32_16x16x32_bf16(a0, bb, acc[ci], 0, 0, 0);
    }
  }
  if (first_layer) {
    float s1[4] = {0.f, 0.f, 0.f, 0.f}, s2[4] = {0.f, 0.f, 0.f, 0.f};
#pragma unroll
    for (int ci = 0; ci < 2; ++ci) {
      int col = (nq * 2 + ci) * 16 + m;
      float bias = bn[col];
#pragma unroll
      for (int r = 0; r < 4; ++r) {
        int row = r0 + q * 4 + r;
        float v = x[(size_t)row * DD + col] + acc[ci][r] + bias;
        xc[ci * 4 + r] = v;
        s1[r] += v; s2[r] += v * v;
      }
    }
#pragma unroll
    for (int r = 0; r < 4; ++r) {
      s1[r] += __shfl_xor(s1[r], 1); s2[r] += __shfl_xor(s2[r], 1);
      s1[r] += __shfl_xor(s1[r], 2); s2[r] += __shfl_xor(s2[r], 2);
      s1[r] += __shfl_xor(s1[r], 4); s2[r] += __shfl_xor(s2[r], 4);
      s1[r] += __shfl_xor(s1[r], 8); s2[r] += __shfl_xor(s2[r], 8);
    }
    float* red = (float*)redc;
    int rl = mt * 16 + q * 4;
    __syncthreads();
    if (m == 0) {
#pragma unroll
      for (int r = 0; r < 4; ++r) {
        red[(rl + r) * 4 + nq] = s1[r];
        red[128 + (rl + r) * 4 + nq] = s2[r];
      }
    }
    __syncthreads();
    float mu[4], rv[4];
#pragma unroll
    for (int r = 0; r < 4; ++r) {
      float t1 = red[(rl + r) * 4] + red[(rl + r) * 4 + 1] +
                 red[(rl + r) * 4 + 2] + red[(rl + r) * 4 + 3];
      float t2 = red[128 + (rl + r) * 4] + red[128 + (rl + r) * 4 + 1] +
                 red[128 + (rl + r) * 4 + 2] + red[128 + (rl + r) * 4 + 3];
      mu[r] = t1 * (1.0f / 128.0f);
      float var = t2 * (1.0f / 128.0f) - mu[r] * mu[r];
      rv[r] = rsqrtf(var + 1e-5f);
    }
#pragma unroll
    for (int ci = 0; ci < 2; ++ci) {
      int col = (nq * 2 + ci) * 16 + m;
      float gm = gamma[col], bt = beta[col];
#pragma unroll
      for (int r = 0; r < 4; ++r) {
        int row = r0 + q * 4 + r;
        float hh = gelu((xc[ci * 4 + r] - mu[r]) * rv[r] * gm + bt);
        ah[(size_t)row * AHS + 256 + col] = f2bf(hh);
      }
    }
  } else {
#pragma unroll
    for (int ci = 0; ci < 2; ++ci) {
      int col = (nq * 2 + ci) * 16 + m;
      float bias = bn[col];
#pragma unroll
      for (int r = 0; r < 4; ++r) {
        int row = r0 + q * 4 + r;
        x[(size_t)row * DD + col] = xc[ci * 4 + r] + acc[ci][r] + bias;
      }
    }
  }
}

// ---------------------------------------------------------------------------
// 32-row internal GEMM tile with SCATTERED rows: t = tbase+local, k = (t==63)?
// 1 : t+1, row = subtree-sb heap node. x0 preloaded in xc (no x read).
__device__ __forceinline__ void ph_gemm32s(char* redc, int b, int sb, int tbase,
                                           unsigned short* ah,
                                           const unsigned short* __restrict__ wfl,
                                           const float* __restrict__ bn,
                                           float* __restrict__ x, int hoff_in,
                                           const float* __restrict__ gamma,
                                           const float* __restrict__ beta,
                                           float* xc, int first_layer) {
  int wave = threadIdx.x >> 6, lane = threadIdx.x & 63;
  int mt = wave >> 2, nq = wave & 3;
  int m = lane & 15, q = lane >> 4;
  int tA = tbase + mt * 16 + m;
  int kA = (tA == 63) ? 1 : tA + 1;
  int lvA = 31 - __clz(kA);
  int rowA = b * NN + (((16 + sb) << lvA) | (kA - (1 << lvA)));
  int rowO[4];
#pragma unroll
  for (int r = 0; r < 4; ++r) {
    int t = tbase + mt * 16 + q * 4 + r;
    int k = (t == 63) ? 1 : t + 1;
    int lv = 31 - __clz(k);
    rowO[r] = b * NN + (((16 + sb) << lv) | (k - (1 << lv)));
  }
  const unsigned short* arow = ah + (size_t)rowA * AHS + q * 8;
  const bf16x8* B = (const bf16x8*)wfl + lane;
  floatx4 acc[2];
  acc[0] = (floatx4){0.f, 0.f, 0.f, 0.f};
  acc[1] = (floatx4){0.f, 0.f, 0.f, 0.f};
#pragma unroll
  for (int kc = 0; kc < 8; ++kc) {
    int koff = (kc < 4) ? kc * 32 : hoff_in + (kc - 4) * 32;
    bf16x8 a0 = *(const bf16x8*)(arow + koff);
#pragma unroll
    for (int ci = 0; ci < 2; ++ci) {
      bf16x8 bb = B[(kc * 8 + nq * 2 + ci) * 64];
      acc[ci] = __builtin_amdgcn_mfma_f32_16x16x32_bf16(a0, bb, acc[ci], 0, 0, 0);
    }
  }
  if (first_layer) {
    float s1[4] = {0.f, 0.f, 0.f, 0.f}, s2[4] = {0.f, 0.f, 0.f, 0.f};
#pragma unroll
    for (int ci = 0; ci < 2; ++ci) {
      int col = (nq * 2 + ci) * 16 + m;
      float bias = bn[col];
#pragma unroll
      for (int r = 0; r < 4; ++r) {
        float v = xc[ci * 4 + r] + acc[ci][r] + bias;
        xc[ci * 4 + r] = v;
        s1[r] += v; s2[r] += v * v;
      }
    }
#pragma unroll
    for (int r = 0; r < 4; ++r) {
      s1[r] += __shfl_xor(s1[r], 1); s2[r] += __shfl_xor(s2[r], 1);
      s1[r] += __shfl_xor(s1[r], 2); s2[r] += __shfl_xor(s2[r], 2);
      s1[r] += __shfl_xor(s1[r], 4); s2[r] += __shfl_xor(s2[r], 4);
      s1[r] += __shfl_xor(s1[r], 8); s2[r] += __shfl_xor(s2[r], 8);
    }
    float* red = (float*)redc;
    int rl = mt * 16 + q * 4;
    __syncthreads();
    if (m == 0) {
#pragma unroll
      for (int r = 0; r < 4; ++r) {
        red[(rl + r) * 4 + nq] = s1[r];
        red[128 + (rl + r) * 4 + nq] = s2[r];
      }
    }
    __syncthreads();
    float mu[4], rv[4];
#pragma unroll
    for (int r = 0; r < 4; ++r) {
      float t1 = red[(rl + r) * 4] + red[(rl + r) * 4 + 1] +
                 red[(rl + r) * 4 + 2] + red[(rl + r) * 4 + 3];
      float t2 = red[128 + (rl + r) * 4] + red[128 + (rl + r) * 4 + 1] +
                 red[128 + (rl + r) * 4 + 2] + red[128 + (rl + r) * 4 + 3];
      mu[r] = t1 * (1.0f / 128.0f);
      float var = t2 * (1.0f / 128.0f) - mu[r] * mu[r];
      rv[r] = rsqrtf(var + 1e-5f);
    }
#pragma unroll
    for (int ci = 0; ci < 2; ++ci) {
      int col = (nq * 2 + ci) * 16 + m;
      float gm = gamma[col], bt = beta[col];
#pragma unroll
      for (int r = 0; r < 4; ++r) {
        float hh = gelu((xc[ci * 4 + r] - mu[r]) * rv[r] * gm + bt);
        ah[(size_t)rowO[r] * AHS + 256 + col] = f2bf(hh);
      }
    }
  } else {
#pragma unroll
    for (int ci = 0; ci < 2; ++ci) {
      int col = (nq * 2 + ci) * 16 + m;
      float bias = bn[col];
#pragma unroll
      for (int r = 0; r < 4; ++r)
        x[(size_t)rowO[r] * DD + col] = xc[ci * 4 + r] + acc[ci][r] + bias;
    }
  }
}

// ---------------------------------------------------------------------------
// 16-row top GEMM tile (rows 0..15 of batch b). 8 waves = 8 col-tiles.
__device__ __forceinline__ void ph_gemm16t(char* redc, int b,
                                           unsigned short* ah,
                                           const unsigned short* __restrict__ wfl,
                                           const float* __restrict__ bn,
                                           float* __restrict__ x, int hoff_in,
                                           const float* __restrict__ gamma,
                                           const float* __restrict__ beta,
                                           float* xc, int first_layer) {
  int ct = threadIdx.x >> 6, lane = threadIdx.x & 63;
  int m = lane & 15, q = lane >> 4;
  const unsigned short* arow = ah + (size_t)(b * NN + m) * AHS + q * 8;
  const bf16x8* B = (const bf16x8*)wfl + lane;
  floatx4 acc = (floatx4){0.f, 0.f, 0.f, 0.f};
#pragma unroll
  for (int kc = 0; kc < 8; ++kc) {
    int koff = (kc < 4) ? kc * 32 : hoff_in + (kc - 4) * 32;
    bf16x8 a0 = *(const bf16x8*)(arow + koff);
    bf16x8 bb = B[(kc * 8 + ct) * 64];
    acc = __builtin_amdgcn_mfma_f32_16x16x32_bf16(a0, bb, acc, 0, 0, 0);
  }
  int col = ct * 16 + m;
  float bias = bn[col];
  if (first_layer) {
    float s1[4], s2[4];
#pragma unroll
    for (int r = 0; r < 4; ++r) {
      float v = xc[r] + acc[r] + bias;
      xc[r] = v; s1[r] = v; s2[r] = v * v;
    }
#pragma unroll
    for (int r = 0; r < 4; ++r) {
      s1[r] += __shfl_xor(s1[r], 1); s2[r] += __shfl_xor(s2[r], 1);
      s1[r] += __shfl_xor(s1[r], 2); s2[r] += __shfl_xor(s2[r], 2);
      s1[r] += __shfl_xor(s1[r], 4); s2[r] += __shfl_xor(s2[r], 4);
      s1[r] += __shfl_xor(s1[r], 8); s2[r] += __shfl_xor(s2[r], 8);
    }
    float* red = (float*)redc;
    __syncthreads();
    if (m == 0) {
#pragma unroll
      for (int r = 0; r < 4; ++r) {
        red[(q * 4 + r) * 8 + ct] = s1[r];
        red[128 + (q * 4 + r) * 8 + ct] = s2[r];
      }
    }
    __syncthreads();
#pragma unroll
    for (int r = 0; r < 4; ++r) {
      float t1 = 0.f, t2 = 0.f;
#pragma unroll
      for (int j = 0; j < 8; ++j) {
        t1 += red[(q * 4 + r) * 8 + j];
        t2 += red[128 + (q * 4 + r) * 8 + j];
      }
      float mu = t1 * (1.0f / 128.0f);
      float var = t2 * (1.0f / 128.0f) - mu * mu;
      float rv = rsqrtf(var + 1e-5f);
      float hh = gelu((xc[r] - mu) * rv * gamma[col] + beta[col]);
      ah[(size_t)(b * NN + q * 4 + r) * AHS + 256 + col] = f2bf(hh);
    }
  } else {
#pragma unroll
    for (int r = 0; r < 4; ++r)
      x[(size_t)(b * NN + q * 4 + r) * DD + col] = xc[r] + acc[r] + bias;
  }
}

// ---------------------------------------------------------------------------
// Megakernel: 8 groups x 32 blocks. 2 group barriers + 16-flag wait (block 0).
__global__ __launch_bounds__(NT, 1) void k_mega(
    const float* __restrict__ elements, const float* __restrict__ ln_gamma,
    const float* __restrict__ ln_beta, const float* __restrict__ w_nei,
    const float* __restrict__ b_nei, const float* __restrict__ w_root,
    const int* __restrict__ srcv, const int* __restrict__ dstv, int E,
    float* __restrict__ x, int* s0a, int* s1a, float* lvl4, float* sroot,
    unsigned short* wf, unsigned short* ah, int* bar) {
  __shared__ __align__(16) char smem[65536];
  int bid = blockIdx.x, tid = threadIdx.x;
  int b = bid >> 5, gb = bid & 31;
  int Eb = E >> 3;
  unsigned short* wfg = wf + (size_t)b * 65536;
  float xcl[8], xci[16], xct[4];

  // ---- P0: tree (gb 0-15, stashes xci) || CSR (16-23) || repack (24-31) ----
  if (gb < 16) {
    ph_tree(smem, b, gb, elements, x, lvl4, ah, ln_gamma, ln_beta, sroot, xci);
  } else if (gb < 24) {
    int base = b * Eb;
    for (int i = base + (gb - 16) * NT + tid; i < base + Eb; i += 8 * NT) {
      int dv = dstv[i];
      if (i == 0 || dstv[i - 1] != dv) s0a[dv] = i;
      if (i == base + Eb - 1 || dstv[i + 1] != dv) s1a[dv] = i + 1;
    }
  } else {
    int gi = (gb - 24) * NT + tid;   // 0..4095 frag units
    int lane = gi & 63, ct = (gi >> 6) & 7, kc = gi >> 9;
    int n = ct * 16 + (lane & 15);
    int k = kc * 32 + (lane >> 4) * 8;
    int kk = k & 127;
#pragma unroll
    for (int l = 0; l < 2; ++l) {
      const float* w = (k < 128) ? (w_nei + (size_t)l * DD * DD)
                                 : (w_root + (size_t)l * DD * DD);
      unsigned short* o = wfg + (size_t)l * 32768 + (size_t)gi * 8;
#pragma unroll
      for (int j = 0; j < 8; ++j) o[j] = f2bf(w[(size_t)(kk + j) * DD + n]);
    }
  }
  gbarN(bar, 0);

  // ---- P1 (layer 0) ----
  if (gb == 0) {
    ph_top(smem, b, lvl4, ah, ln_gamma, ln_beta);      // xs in LDS, h->ah
    {                                                  // stash xct from xs
      int wv = tid >> 6, ln = tid & 63, m_ = ln & 15, q_ = ln >> 4;
      float (*xs)[DD] = (float(*)[DD])smem;
#pragma unroll
      for (int r = 0; r < 4; ++r) xct[r] = xs[q_ * 4 + r][wv * 16 + m_];
    }
    if (tid < 128) ph_topfin(b, sroot, ah, 128);
    __syncthreads();
    ph_gemm16t(smem + 61440, b, ah, wfg, b_nei, x, 128,
               ln_gamma + DD, ln_beta + DD, xct, 1);
    __syncthreads();
  }
  ph_leafagg(smem, b, gb, srcv, s0a, s1a, ah, 128, lvl4, ln_gamma, ln_beta, 1);
  __syncthreads();
  ph_gemm32(smem + 61440, b * NN + 1024 + gb * 32, ah, wfg, b_nei, x, 128,
            ln_gamma + DD, ln_beta + DD, xcl, 1);
  if (gb < 16) {
    ph_gemm32s(smem + 61440, b, gb, 0, ah, wfg, b_nei, x, 128,
               ln_gamma + DD, ln_beta + DD, xci, 1);
    ph_gemm32s(smem + 61440, b, gb, 32, ah, wfg, b_nei, x, 128,
               ln_gamma + DD, ln_beta + DD, xci + 8, 1);
  }
  gbarN(bar, 1);

  // ---- P2 (layer 1): no group barrier; only block 0 waits on 16 flags ----
  if (gb < 16) {
    ph_aggsub(smem, b, gb, ah, sroot);
    __syncthreads();
    if (tid == 0) {
      __threadfence();
      __hip_atomic_store(bar + 1024 + b * 64 + gb * 4, 1, __ATOMIC_RELAXED,
                         __HIP_MEMORY_SCOPE_AGENT);
    }
  }
  ph_leafagg(smem, b, gb, srcv, s0a, s1a, ah, 256, lvl4, ln_gamma, ln_beta, 0);
  __syncthreads();
  ph_gemm32(smem + 61440, b * NN + 1024 + gb * 32, ah, wfg + 32768, b_nei + DD,
            x, 256, ln_gamma, ln_beta, xcl, 0);
  if (gb < 16) {
    ph_gemm32s(smem + 61440, b, gb, 0, ah, wfg + 32768, b_nei + DD, x, 256,
               ln_gamma, ln_beta, xci, 0);
    ph_gemm32s(smem + 61440, b, gb, 32, ah, wfg + 32768, b_nei + DD, x, 256,
               ln_gamma, ln_beta, xci + 8, 0);
  }
  if (gb == 0) {
    if (tid < 16) {
      while (!__hip_atomic_load(bar + 1024 + b * 64 + tid * 4, __ATOMIC_RELAXED,
                                __HIP_MEMORY_SCOPE_AGENT))
        __builtin_amdgcn_s_sleep(2);
      __threadfence();
    }
    __syncthreads();
    if (tid < 128) ph_topfin(b, sroot, ah, 256);
    __syncthreads();
    ph_gemm16t(smem + 61440, b, ah, wfg + 32768, b_nei + DD, x, 256,
               ln_gamma, ln_beta, xct, 0);
  }
}

// ---------------------------------------------------------------------------
extern "C" void kernel_launch(void* const* d_in, const int* in_sizes, int n_in,
                              void* d_out, int out_size, void* d_ws, size_t ws_size,
                              hipStream_t stream) {
  const float* elements = (const float*)d_in[0];
  const float* ln_gamma = (const float*)d_in[1];
  const float* ln_beta  = (const float*)d_in[2];
  const float* w_nei    = (const float*)d_in[3];
  const float* b_nei    = (const float*)d_in[4];
  const float* w_root   = (const float*)d_in[5];
  const int*   edge     = (const int*)d_in[6];
  int E = in_sizes[6] / 2;
  const int* srcv = edge;
  const int* dstv = edge + E;
  float* x = (float*)d_out;

  char* ws = (char*)d_ws;
  int*            bar   = (int*)ws;                         // 8 KB used
  int*            s0    = (int*)(ws + 65536);               // 64 KB
  int*            s1    = (int*)(ws + 131072);              // 64 KB
  float*          lvl4  = (float*)(ws + 196608);            // 64 KB
  float*          sroot = (float*)(ws + 262144);            // 64 KB
  unsigned short* wf    = (unsigned short*)(ws + 327680);   // 1 MB (8 copies)
  unsigned short* ah    = (unsigned short*)(ws + 327680 + 1048576);  // 12.6 MB

  hipMemsetAsync(bar, 0, 8192, stream);
  k_mega<<<dim3(NB), dim3(NT), 0, stream>>>(
      elements, ln_gamma, ln_beta, w_nei, b_nei, w_root,
      srcv, dstv, E, x, s0, s1, lvl4, sroot, wf, ah, bar);
}

// Round 13
// 198.838 us; speedup vs baseline: 1.1485x; 1.0241x over previous
//
#include <hip/hip_runtime.h>
#include <hip/hip_bf16.h>

// Problem constants (fixed by the reference file)
#define LEAFN 1024
#define NN    2048            // nodes per batch incl. global node 0
#define BATCH 8
#define DD    128
#define ROWS  (BATCH*NN)      // 16384
#define AHS   384             // ah row stride: [agg(128) | hL0(128) | hL1(128)]
#define NB    256             // megakernel grid (1 block/CU)
#define NT    512             // threads per block (8 waves)

// ln(10000)/32
#define LOG1E4_OVER_32 0.28782313662425575f

typedef __bf16 bf16x8 __attribute__((ext_vector_type(8)));
typedef float  floatx4 __attribute__((ext_vector_type(4)));
typedef float  floatx2 __attribute__((ext_vector_type(2)));

__device__ __forceinline__ float bf2f(unsigned short u) {
  return __uint_as_float(((unsigned)u) << 16);
}
__device__ __forceinline__ unsigned short f2bf(float f) {
  unsigned u = __float_as_uint(f);
  u += 0x7FFFu + ((u >> 16) & 1u);          // round-to-nearest-even
  return (unsigned short)(u >> 16);
}
__device__ __forceinline__ float gelu(float v) {
  return 0.5f * v * (1.0f + erff(v * 0.70710678118f));
}
__device__ __forceinline__ floatx2 bfpair(unsigned u) {
  floatx2 r;
  r[0] = __uint_as_float(u << 16);
  r[1] = __uint_as_float(u & 0xffff0000u);
  return r;
}

__device__ __forceinline__ float enc_val(int node, int d) {
  float hp, vp;
  if (node == 0) { hp = -0.5f; vp = -1.0f; }
  else {
    int v = 31 - __clz(node);
    hp = (float)(node - (1 << v));
    vp = (float)v;
  }
  float pos = (d < 64) ? hp : vp;
  int i = ((d < 64) ? d : (d - 64)) >> 1;
  float inv = expf(-(float)i * LOG1E4_OVER_32);
  float ang = pos * inv;
  return (d & 1) ? cosf(ang) : sinf(ang);
}

// ---------------------------------------------------------------------------
// Per-group barrier over 32 blocks. Group g = bid & 7 -> XCD-affine under the
// observed round-robin dispatch (performance heuristic only; agent-scope
// fences keep this correct under ANY block->XCD mapping).
__device__ __forceinline__ void gbarN(int* bar, int slot) {
  __syncthreads();
  if (threadIdx.x == 0) {
    int g = blockIdx.x & 7;
    int* base = bar + (slot * 8 + g) * 64;
    __threadfence();                           // release (L2 wb)
    if (__hip_atomic_fetch_add(base, 1, __ATOMIC_RELAXED,
                               __HIP_MEMORY_SCOPE_AGENT) == 31)
      __hip_atomic_store(base + 32, 1, __ATOMIC_RELAXED,
                         __HIP_MEMORY_SCOPE_AGENT);
    while (!__hip_atomic_load(base + 32, __ATOMIC_RELAXED,
                              __HIP_MEMORY_SCOPE_AGENT))
      __builtin_amdgcn_s_sleep(1);
    __threadfence();                           // acquire (L2 inv)
  }
  __syncthreads();
}

// ---------------------------------------------------------------------------
// Tree build + layer-0 LN/GELU + in-LDS subtree sums; stashes x0 of the 64
// internal-gemm tile rows (subtree heap order + dup) into xci registers.
__device__ __forceinline__ void ph_tree(char* smemc, int b, int s,
                                        const float* __restrict__ elements,
                                        float* __restrict__ x,
                                        float* __restrict__ lvl4,
                                        unsigned short* __restrict__ ah,
                                        const float* __restrict__ gamma,
                                        const float* __restrict__ beta,
                                        float* __restrict__ sroot,
                                        float* xci) {
  float* sm = (float*)smemc;                  // 127*128 floats = 63.5 KB
  int tid = threadIdx.x;
  const float4* src = (const float4*)(elements + (size_t)(b * LEAFN + s * 64) * DD);
  for (int i = tid; i < 2048; i += NT) {
    int f = i * 4;
    int j = f >> 7, d = f & 127;
    *(float4*)&sm[(63 + j) * DD + d] = src[i];
  }
  __syncthreads();
  for (int lv = 5; lv >= 0; --lv) {
    int nodes = 1 << lv;
    for (int idx = tid; idx < nodes * DD; idx += NT) {
      int k = nodes + (idx >> 7);
      int d = idx & 127;
      sm[(k - 1) * DD + d] = 0.5f * (sm[(2 * k - 1) * DD + d] + sm[(2 * k) * DD + d]);
    }
    __syncthreads();
  }
  if (tid < DD) lvl4[(b * 16 + s) * DD + tid] = sm[tid];
  __syncthreads();
  // x = feat + enc; keep in sm; write global x ONLY for leaf rows (k>=64)
  for (int idx = tid; idx < 127 * DD; idx += NT) {
    int k = (idx >> 7) + 1;
    int d = idx & 127;
    int lv = 31 - __clz(k);
    int g = ((16 + s) << lv) | (k - (1 << lv));
    float xv = sm[idx] + enc_val(g, d);
    if (k >= 64) x[((size_t)(b * NN + g)) * DD + d] = xv;
    sm[idx] = xv;
  }
  __syncthreads();
  // stash x0 for this block's internal gemm tiles (2 x 32 rows, dup t=63->k=1)
  {
    int wave = tid >> 6, lane = tid & 63;
    int mt = wave >> 2, nq = wave & 3;
    int m = lane & 15, q = lane >> 4;
#pragma unroll
    for (int c = 0; c < 2; ++c)
#pragma unroll
      for (int ci = 0; ci < 2; ++ci)
#pragma unroll
        for (int r = 0; r < 4; ++r) {
          int t = c * 32 + mt * 16 + q * 4 + r;
          int k = (t == 63) ? 1 : t + 1;
          int d = (nq * 2 + ci) * 16 + m;
          xci[c * 8 + ci * 4 + r] = sm[(k - 1) * DD + d];
        }
  }
  __syncthreads();
  // LN + GELU: h -> ah(+128) AND h overwrites sm (fp32)
  {
    int sub = tid & 7, dp = sub * 16;
    for (int rr = tid >> 3; rr < 127; rr += NT / 8) {
      float v[16], s1 = 0.f, s2 = 0.f;
#pragma unroll
      for (int j = 0; j < 16; ++j) { v[j] = sm[rr * DD + dp + j]; s1 += v[j]; s2 += v[j] * v[j]; }
      s1 += __shfl_xor(s1, 1); s2 += __shfl_xor(s2, 1);
      s1 += __shfl_xor(s1, 2); s2 += __shfl_xor(s2, 2);
      s1 += __shfl_xor(s1, 4); s2 += __shfl_xor(s2, 4);
      float mu = s1 * (1.0f / 128.0f);
      float var = s2 * (1.0f / 128.0f) - mu * mu;
      float rinv = rsqrtf(var + 1e-5f);
      int k = rr + 1, lv = 31 - __clz(k);
      int g = ((16 + s) << lv) | (k - (1 << lv));
      __attribute__((aligned(16))) unsigned short o[16];
#pragma unroll
      for (int j = 0; j < 16; ++j) {
        float hv = gelu((v[j] - mu) * rinv * gamma[dp + j] + beta[dp + j]);
        o[j] = f2bf(hv);
        sm[rr * DD + dp + j] = hv;
      }
      unsigned short* dst = &ah[(size_t)(b * NN + g) * AHS + 128 + dp];
      *(uint4*)&dst[0] = *(uint4*)&o[0];
      *(uint4*)&dst[8] = *(uint4*)&o[8];
    }
  }
  __syncthreads();
  // subtree-sum pyramid in LDS; agg (closed-form deg) -> ah(+0)
  for (int lv = 5; lv >= 0; --lv) {
    int nk = 1 << lv;
    float inv = 1.0f / (float)((1 << (7 - lv)) - 2);
    for (int idx = tid; idx < nk * DD; idx += NT) {
      int k = nk + (idx >> 7);
      int d = idx & 127;
      float S = sm[(2 * k - 1) * DD + d] + sm[(2 * k) * DD + d];
      if (lv < 5) S += sm[(4 * k - 1) * DD + d] + sm[(4 * k + 1) * DD + d];
      sm[(2 * k - 1) * DD + d] = S;
      int g = ((16 + s) << lv) | (k - nk);
      ah[(size_t)(b * NN + g) * AHS + d] = f2bf(S * inv);
    }
    __syncthreads();
  }
  if (tid < DD) sroot[(size_t)(b * 16 + s) * DD + tid] = sm[DD + tid];
}

// ---------------------------------------------------------------------------
// Top nodes 0..15: x0 into LDS xs (no global write), layer-0 h -> ah.
__device__ __forceinline__ void ph_top(char* smemc, int b,
                                       const float* __restrict__ lvl4,
                                       unsigned short* __restrict__ ah,
                                       const float* __restrict__ gamma,
                                       const float* __restrict__ beta) {
  float (*xs)[DD] = (float(*)[DD])smemc;      // 8 KB
  int tid = threadIdx.x;
  if (tid < 128) {
    int d = tid;
    float v[16];
    for (int j = 0; j < 16; ++j) v[j] = lvl4[(b * 16 + j) * DD + d];
    for (int j = 0; j < 8; ++j) v[j] = 0.5f * (v[2 * j] + v[2 * j + 1]);
    for (int j = 0; j < 8; ++j) xs[8 + j][d] = v[j] + enc_val(8 + j, d);
    for (int j = 0; j < 4; ++j) v[j] = 0.5f * (v[2 * j] + v[2 * j + 1]);
    for (int j = 0; j < 4; ++j) xs[4 + j][d] = v[j] + enc_val(4 + j, d);
    for (int j = 0; j < 2; ++j) v[j] = 0.5f * (v[2 * j] + v[2 * j + 1]);
    for (int j = 0; j < 2; ++j) xs[2 + j][d] = v[j] + enc_val(2 + j, d);
    v[0] = 0.5f * (v[0] + v[1]);
    xs[1][d] = v[0] + enc_val(1, d);
    xs[0][d] = -1.0f + enc_val(0, d);
  }
  __syncthreads();
  if (tid < 128) {
    int rr = tid >> 3, sub = tid & 7, dp = sub * 16;
    float w[16], s1 = 0.f, s2 = 0.f;
#pragma unroll
    for (int j = 0; j < 16; ++j) { w[j] = xs[rr][dp + j]; s1 += w[j]; s2 += w[j] * w[j]; }
    s1 += __shfl_xor(s1, 1); s2 += __shfl_xor(s2, 1);
    s1 += __shfl_xor(s1, 2); s2 += __shfl_xor(s2, 2);
    s1 += __shfl_xor(s1, 4); s2 += __shfl_xor(s2, 4);
    float mu = s1 * (1.0f / 128.0f);
    float var = s2 * (1.0f / 128.0f) - mu * mu;
    float rinv = rsqrtf(var + 1e-5f);
    __attribute__((aligned(16))) unsigned short o[16];
#pragma unroll
    for (int j = 0; j < 16; ++j)
      o[j] = f2bf(gelu((w[j] - mu) * rinv * gamma[dp + j] + beta[dp + j]));
    unsigned short* dst = &ah[(size_t)(b * NN + rr) * AHS + 128 + dp];
    *(uint4*)&dst[0] = *(uint4*)&o[0];
    *(uint4*)&dst[8] = *(uint4*)&o[8];
  }
  __syncthreads();
}

// ---------------------------------------------------------------------------
// Subtree sums for L1: reads h' from ah(+256), agg -> ah(+0), sroot.
__device__ __forceinline__ void ph_aggsub(char* smemc, int b, int s,
                                          unsigned short* ah,
                                          float* __restrict__ sroot) {
  floatx4 (*S)[32] = (floatx4(*)[32])smemc;   // 32 KB
  int tid = threadIdx.x;
  for (int idx = tid; idx < 32 * 32; idx += NT) {
    int k = 32 + (idx >> 5), q = idx & 31;
    int c = (16 + s) * 64 + (2 * k - 64);
    size_t a0 = (size_t)(b * NN + c) * AHS + 256 + q * 4;
    ushort4 u0 = *(const ushort4*)&ah[a0];
    ushort4 u1 = *(const ushort4*)&ah[a0 + AHS];
    floatx4 v;
    v[0] = bf2f(u0.x) + bf2f(u1.x);
    v[1] = bf2f(u0.y) + bf2f(u1.y);
    v[2] = bf2f(u0.z) + bf2f(u1.z);
    v[3] = bf2f(u0.w) + bf2f(u1.w);
    S[k][q] = v;
    int g = (16 + s) * 32 + (k - 32);
    int r = b * NN + g;
    ushort4 o;
    o.x = f2bf(v[0] * 0.5f); o.y = f2bf(v[1] * 0.5f);
    o.z = f2bf(v[2] * 0.5f); o.w = f2bf(v[3] * 0.5f);
    *(ushort4*)&ah[(size_t)r * AHS + q * 4] = o;
  }
  __syncthreads();
  for (int lv = 4; lv >= 0; --lv) {
    int nk = 1 << lv;
    float inv = 1.0f / (float)((1 << (7 - lv)) - 2);
    for (int idx = tid; idx < nk * 32; idx += NT) {
      int k = nk + (idx >> 5), q = idx & 31;
      int c = ((16 + s) << (lv + 1)) | (2 * k - 2 * nk);
      size_t a0 = (size_t)(b * NN + c) * AHS + 256 + q * 4;
      ushort4 u0 = *(const ushort4*)&ah[a0];
      ushort4 u1 = *(const ushort4*)&ah[a0 + AHS];
      floatx4 sc0 = S[2 * k][q], sc1 = S[2 * k + 1][q];
      floatx4 v;
      v[0] = bf2f(u0.x) + bf2f(u1.x) + sc0[0] + sc1[0];
      v[1] = bf2f(u0.y) + bf2f(u1.y) + sc0[1] + sc1[1];
      v[2] = bf2f(u0.z) + bf2f(u1.z) + sc0[2] + sc1[2];
      v[3] = bf2f(u0.w) + bf2f(u1.w) + sc0[3] + sc1[3];
      S[k][q] = v;
      int g = ((16 + s) << lv) | (k - nk);
      int r = b * NN + g;
      ushort4 o;
      o.x = f2bf(v[0] * inv); o.y = f2bf(v[1] * inv);
      o.z = f2bf(v[2] * inv); o.w = f2bf(v[3] * inv);
      *(ushort4*)&ah[(size_t)r * AHS + q * 4] = o;
    }
    __syncthreads();
  }
  for (int q = tid; q < 32; q += NT)
    ((floatx4*)sroot)[(size_t)(b * 16 + s) * 32 + q] = S[1][q];
}

// ---------------------------------------------------------------------------
// Leaf-row gather: per-level LDS window cache; h read at +hoff; agg -> +0.
#define SLACK 10
#define CACHE_ROWS 220
#define CSTRIDE 136
__device__ __forceinline__ void ph_leafagg(char* smemc, int b, int jb,
                                           const int* __restrict__ src,
                                           const int* __restrict__ s0a,
                                           const int* __restrict__ s1a,
                                           unsigned short* ah, int hoff,
                                           const float* __restrict__ lvl4,
                                           const float* __restrict__ gamma,
                                           const float* __restrict__ beta,
                                           int l0patch) {
  unsigned short* cache = (unsigned short*)smemc;  // 59840 B
  int2* wtab = (int2*)(smemc + 60928);             // 11 entries
  int tid = threadIdx.x;
  int li0 = jb * 32;
  int g0 = 1024 + li0, g1 = g0 + 31;

  int lo[11], wd[11], off[11];
  int acc_off = 0;
  for (int cd = 10; cd >= 1; --cd) {
    int a0 = g0 >> (10 - cd), a1 = g1 >> (10 - cd);
    int l = a0 - SLACK, hgh = a1 + SLACK;
    int lvlo = 1 << cd, lvhi = (2 << cd) - 1;
    l = l < lvlo ? lvlo : l;
    hgh = hgh > lvhi ? lvhi : hgh;
    int w = hgh - l + 1;
    if (w < 0) w = 0;
    lo[cd] = l; wd[cd] = w; off[cd] = acc_off; acc_off += w;
  }
  if (tid >= 1 && tid <= 10) {
    int cd = tid;
    wtab[cd] = make_int2(off[cd] - lo[cd], lo[cd] | (wd[cd] << 16));
  }
  int cdmin = l0patch ? 4 : 1;
  for (int cd = 10; cd >= cdmin; --cd) {
    int w = wd[cd];
    for (int t = tid; t < w * 16; t += NT) {
      int row = t >> 4, seg = t & 15;
      *(uint4*)&cache[(off[cd] + row) * CSTRIDE + seg * 8] =
          *(const uint4*)&ah[(size_t)(b * NN + lo[cd] + row) * AHS + hoff + seg * 8];
    }
  }
  if (l0patch && tid < 112) {
    // h rows 2..15 computed locally from lvl4 (mean + enc + LN + GELU)
    int row = 2 + (tid >> 3), sub = tid & 7, dp = sub * 16;
    int dv = 31 - __clz(row);
    int cnt = 1 << (4 - dv);
    int l4r = (row << (4 - dv)) - 16;
    float v[16];
#pragma unroll
    for (int j = 0; j < 16; ++j) v[j] = 0.f;
    for (int c = 0; c < cnt; ++c) {
      const float* p = &lvl4[(size_t)(b * 16 + l4r + c) * DD + dp];
#pragma unroll
      for (int j = 0; j < 16; ++j) v[j] += p[j];
    }
    float sc = 1.0f / (float)cnt;
    float s1 = 0.f, s2 = 0.f;
#pragma unroll
    for (int j = 0; j < 16; ++j) {
      v[j] = v[j] * sc + enc_val(row, dp + j);
      s1 += v[j]; s2 += v[j] * v[j];
    }
    s1 += __shfl_xor(s1, 1); s2 += __shfl_xor(s2, 1);
    s1 += __shfl_xor(s1, 2); s2 += __shfl_xor(s2, 2);
    s1 += __shfl_xor(s1, 4); s2 += __shfl_xor(s2, 4);
    float mu = s1 * (1.0f / 128.0f);
    float var = s2 * (1.0f / 128.0f) - mu * mu;
    float rinv = rsqrtf(var + 1e-5f);
    __attribute__((aligned(16))) unsigned short o[16];
#pragma unroll
    for (int j = 0; j < 16; ++j)
      o[j] = f2bf(gelu((v[j] - mu) * rinv * gamma[dp + j] + beta[dp + j]));
    int cr = off[dv] + (row - lo[dv]);
    *(uint4*)&cache[cr * CSTRIDE + sub * 16] = *(uint4*)&o[0];
    *(uint4*)&cache[cr * CSTRIDE + sub * 16 + 8] = *(uint4*)&o[8];
  }
  __syncthreads();

  int leaf = tid >> 4, c = tid & 15;
  int r = b * NN + 1024 + li0 + leaf;
  int e0 = s0a[r], e1 = s1a[r];
  floatx2 a0 = {0.f, 0.f}, a1 = {0.f, 0.f}, a2 = {0.f, 0.f}, a3 = {0.f, 0.f};
  for (int e = e0; e < e1; ++e) {
    int g = src[e] - b * NN;
    int lv = 31 - __clz(g);
    int2 t = wtab[lv];
    int idx = g - (t.y & 0xffff);
    uint4 u;
    if ((unsigned)idx < (unsigned)(t.y >> 16))
      u = *(const uint4*)&cache[(t.x + g) * CSTRIDE + c * 8];
    else
      u = *(const uint4*)&ah[(size_t)(b * NN + g) * AHS + hoff + c * 8];
    a0 += bfpair(u.x); a1 += bfpair(u.y); a2 += bfpair(u.z); a3 += bfpair(u.w);
  }
  float inv = 1.0f / (float)max(e1 - e0, 1);
  __attribute__((aligned(16))) unsigned short o[8];
  o[0] = f2bf(a0[0] * inv); o[1] = f2bf(a0[1] * inv);
  o[2] = f2bf(a1[0] * inv); o[3] = f2bf(a1[1] * inv);
  o[4] = f2bf(a2[0] * inv); o[5] = f2bf(a2[1] * inv);
  o[6] = f2bf(a3[0] * inv); o[7] = f2bf(a3[1] * inv);
  *(uint4*)&ah[(size_t)r * AHS + c * 8] = *(uint4*)&o[0];
}

// ---------------------------------------------------------------------------
// Finish agg for nodes 0..15 (tid<128); h at +hoff, closed-form deg.
__device__ __forceinline__ void ph_topfin(int b,
                                          const float* __restrict__ sroot,
                                          unsigned short* ah, int hoff) {
  int d = threadIdx.x;
  float S16[16], h16[16], Sv[16];
#pragma unroll
  for (int j = 0; j < 16; ++j) S16[j] = sroot[(size_t)(b * 16 + j) * DD + d];
#pragma unroll
  for (int j = 0; j < 16; ++j)
    h16[j] = bf2f(ah[(size_t)(b * NN + 16 + j) * AHS + hoff + d]);
#pragma unroll
  for (int k = 8; k < 16; ++k)
    Sv[k] = h16[2 * k - 16] + h16[2 * k - 15] + S16[2 * k - 16] + S16[2 * k - 15];
#pragma unroll
  for (int k = 7; k >= 1; --k)
    Sv[k] = bf2f(ah[(size_t)(b * NN + 2 * k) * AHS + hoff + d]) +
            bf2f(ah[(size_t)(b * NN + 2 * k + 1) * AHS + hoff + d]) +
            Sv[2 * k] + Sv[2 * k + 1];
#pragma unroll
  for (int k = 1; k < 16; ++k) {
    int dv = 31 - __clz(k);
    float inv = 1.0f / (float)((1 << (11 - dv)) - 2);
    ah[(size_t)(b * NN + k) * AHS + d] = f2bf(Sv[k] * inv);
  }
  ah[(size_t)(b * NN) * AHS + d] = f2bf(0.0f);
}

// ---------------------------------------------------------------------------
// 32-row leaf GEMM tile (contiguous rows at rowbase). first_layer=1:
// v = x0(global read) + out + bias -> xc regs + LN/GELU h'->+256.
// first_layer=0: x = xc + out + bias (final write).
__device__ __forceinline__ void ph_gemm32(char* redc, int rowbase,
                                          unsigned short* ah,
                                          const unsigned short* __restrict__ wfl,
                                          const float* __restrict__ bn,
                                          float* __restrict__ x, int hoff_in,
                                          const float* __restrict__ gamma,
                                          const float* __restrict__ beta,
                                          float* xc, int first_layer) {
  int wave = threadIdx.x >> 6, lane = threadIdx.x & 63;
  int mt = wave >> 2, nq = wave & 3;
  int r0 = rowbase + mt * 16;
  int m = lane & 15, q = lane >> 4;
  const unsigned short* arow = ah + (size_t)(r0 + m) * AHS + q * 8;
  const bf16x8* B = (const bf16x8*)wfl + lane;
  floatx4 acc[2];
  acc[0] = (floatx4){0.f, 0.f, 0.f, 0.f};
  acc[1] = (floatx4){0.f, 0.f, 0.f, 0.f};
#pragma unroll
  for (int kc = 0; kc < 8; ++kc) {
    int koff = (kc < 4) ? kc * 32 : hoff_in + (kc - 4) * 32;
    bf16x8 a0 = *(const bf16x8*)(arow + koff);
#pragma unroll
    for (int ci = 0; ci < 2; ++ci) {
      bf16x8 bb = B[(kc * 8 + nq * 2 + ci) * 64];
      acc[ci] = __builtin_amdgcn_mfma_f32_16x16x32_bf16(a0, bb, acc[ci], 0, 0, 0);
    }
  }
  if (first_layer) {
    float s1[4] = {0.f, 0.f, 0.f, 0.f}, s2[4] = {0.f, 0.f, 0.f, 0.f};
#pragma unroll
    for (int ci = 0; ci < 2; ++ci) {
      int col = (nq * 2 + ci) * 16 + m;
      float bias = bn[col];
#pragma unroll
      for (int r = 0; r < 4; ++r) {
        int row = r0 + q * 4 + r;
        float v = x[(size_t)row * DD + col] + acc[ci][r] + bias;
        xc[ci * 4 + r] = v;
        s1[r] += v; s2[r] += v * v;
      }
    }
#pragma unroll
    for (int r = 0; r < 4; ++r) {
      s1[r] += __shfl_xor(s1[r], 1); s2[r] += __shfl_xor(s2[r], 1);
      s1[r] += __shfl_xor(s1[r], 2); s2[r] += __shfl_xor(s2[r], 2);
      s1[r] += __shfl_xor(s1[r], 4); s2[r] += __shfl_xor(s2[r], 4);
      s1[r] += __shfl_xor(s1[r], 8); s2[r] += __shfl_xor(s2[r], 8);
    }
    float* red = (float*)redc;
    int rl = mt * 16 + q * 4;
    __syncthreads();
    if (m == 0) {
#pragma unroll
      for (int r = 0; r < 4; ++r) {
        red[(rl + r) * 4 + nq] = s1[r];
        red[128 + (rl + r) * 4 + nq] = s2[r];
      }
    }
    __syncthreads();
    float mu[4], rv[4];
#pragma unroll
    for (int r = 0; r < 4; ++r) {
      float t1 = red[(rl + r) * 4] + red[(rl + r) * 4 + 1] +
                 red[(rl + r) * 4 + 2] + red[(rl + r) * 4 + 3];
      float t2 = red[128 + (rl + r) * 4] + red[128 + (rl + r) * 4 + 1] +
                 red[128 + (rl + r) * 4 + 2] + red[128 + (rl + r) * 4 + 3];
      mu[r] = t1 * (1.0f / 128.0f);
      float var = t2 * (1.0f / 128.0f) - mu[r] * mu[r];
      rv[r] = rsqrtf(var + 1e-5f);
    }
#pragma unroll
    for (int ci = 0; ci < 2; ++ci) {
      int col = (nq * 2 + ci) * 16 + m;
      float gm = gamma[col], bt = beta[col];
#pragma unroll
      for (int r = 0; r < 4; ++r) {
        int row = r0 + q * 4 + r;
        float hh = gelu((xc[ci * 4 + r] - mu[r]) * rv[r] * gm + bt);
        ah[(size_t)row * AHS + 256 + col] = f2bf(hh);
      }
    }
  } else {
#pragma unroll
    for (int ci = 0; ci < 2; ++ci) {
      int col = (nq * 2 + ci) * 16 + m;
      float bias = bn[col];
#pragma unroll
      for (int r = 0; r < 4; ++r) {
        int row = r0 + q * 4 + r;
        x[(size_t)row * DD + col] = xc[ci * 4 + r] + acc[ci][r] + bias;
      }
    }
  }
}

// ---------------------------------------------------------------------------
// 32-row internal GEMM tile with SCATTERED rows: t = tbase+local, k = (t==63)?
// 1 : t+1, row = subtree-sb heap node. x0 preloaded in xc (no x read).
__device__ __forceinline__ void ph_gemm32s(char* redc, int b, int sb, int tbase,
                                           unsigned short* ah,
                                           const unsigned short* __restrict__ wfl,
                                           const float* __restrict__ bn,
                                           float* __restrict__ x, int hoff_in,
                                           const float* __restrict__ gamma,
                                           const float* __restrict__ beta,
                                           float* xc, int first_layer) {
  int wave = threadIdx.x >> 6, lane = threadIdx.x & 63;
  int mt = wave >> 2, nq = wave & 3;
  int m = lane & 15, q = lane >> 4;
  int tA = tbase + mt * 16 + m;
  int kA = (tA == 63) ? 1 : tA + 1;
  int lvA = 31 - __clz(kA);
  int rowA = b * NN + (((16 + sb) << lvA) | (kA - (1 << lvA)));
  int rowO[4];
#pragma unroll
  for (int r = 0; r < 4; ++r) {
    int t = tbase + mt * 16 + q * 4 + r;
    int k = (t == 63) ? 1 : t + 1;
    int lv = 31 - __clz(k);
    rowO[r] = b * NN + (((16 + sb) << lv) | (k - (1 << lv)));
  }
  const unsigned short* arow = ah + (size_t)rowA * AHS + q * 8;
  const bf16x8* B = (const bf16x8*)wfl + lane;
  floatx4 acc[2];
  acc[0] = (floatx4){0.f, 0.f, 0.f, 0.f};
  acc[1] = (floatx4){0.f, 0.f, 0.f, 0.f};
#pragma unroll
  for (int kc = 0; kc < 8; ++kc) {
    int koff = (kc < 4) ? kc * 32 : hoff_in + (kc - 4) * 32;
    bf16x8 a0 = *(const bf16x8*)(arow + koff);
#pragma unroll
    for (int ci = 0; ci < 2; ++ci) {
      bf16x8 bb = B[(kc * 8 + nq * 2 + ci) * 64];
      acc[ci] = __builtin_amdgcn_mfma_f32_16x16x32_bf16(a0, bb, acc[ci], 0, 0, 0);
    }
  }
  if (first_layer) {
    float s1[4] = {0.f, 0.f, 0.f, 0.f}, s2[4] = {0.f, 0.f, 0.f, 0.f};
#pragma unroll
    for (int ci = 0; ci < 2; ++ci) {
      int col = (nq * 2 + ci) * 16 + m;
      float bias = bn[col];
#pragma unroll
      for (int r = 0; r < 4; ++r) {
        float v = xc[ci * 4 + r] + acc[ci][r] + bias;
        xc[ci * 4 + r] = v;
        s1[r] += v; s2[r] += v * v;
      }
    }
#pragma unroll
    for (int r = 0; r < 4; ++r) {
      s1[r] += __shfl_xor(s1[r], 1); s2[r] += __shfl_xor(s2[r], 1);
      s1[r] += __shfl_xor(s1[r], 2); s2[r] += __shfl_xor(s2[r], 2);
      s1[r] += __shfl_xor(s1[r], 4); s2[r] += __shfl_xor(s2[r], 4);
      s1[r] += __shfl_xor(s1[r], 8); s2[r] += __shfl_xor(s2[r], 8);
    }
    float* red = (float*)redc;
    int rl = mt * 16 + q * 4;
    __syncthreads();
    if (m == 0) {
#pragma unroll
      for (int r = 0; r < 4; ++r) {
        red[(rl + r) * 4 + nq] = s1[r];
        red[128 + (rl + r) * 4 + nq] = s2[r];
      }
    }
    __syncthreads();
    float mu[4], rv[4];
#pragma unroll
    for (int r = 0; r < 4; ++r) {
      float t1 = red[(rl + r) * 4] + red[(rl + r) * 4 + 1] +
                 red[(rl + r) * 4 + 2] + red[(rl + r) * 4 + 3];
      float t2 = red[128 + (rl + r) * 4] + red[128 + (rl + r) * 4 + 1] +
                 red[128 + (rl + r) * 4 + 2] + red[128 + (rl + r) * 4 + 3];
      mu[r] = t1 * (1.0f / 128.0f);
      float var = t2 * (1.0f / 128.0f) - mu[r] * mu[r];
      rv[r] = rsqrtf(var + 1e-5f);
    }
#pragma unroll
    for (int ci = 0; ci < 2; ++ci) {
      int col = (nq * 2 + ci) * 16 + m;
      float gm = gamma[col], bt = beta[col];
#pragma unroll
      for (int r = 0; r < 4; ++r) {
        float hh = gelu((xc[ci * 4 + r] - mu[r]) * rv[r] * gm + bt);
        ah[(size_t)rowO[r] * AHS + 256 + col] = f2bf(hh);
      }
    }
  } else {
#pragma unroll
    for (int ci = 0; ci < 2; ++ci) {
      int col = (nq * 2 + ci) * 16 + m;
      float bias = bn[col];
#pragma unroll
      for (int r = 0; r < 4; ++r)
        x[(size_t)rowO[r] * DD + col] = xc[ci * 4 + r] + acc[ci][r] + bias;
    }
  }
}

// ---------------------------------------------------------------------------
// 16-row top GEMM tile (rows 0..15 of batch b). 8 waves = 8 col-tiles.
__device__ __forceinline__ void ph_gemm16t(char* redc, int b,
                                           unsigned short* ah,
                                           const unsigned short* __restrict__ wfl,
                                           const float* __restrict__ bn,
                                           float* __restrict__ x, int hoff_in,
                                           const float* __restrict__ gamma,
                                           const float* __restrict__ beta,
                                           float* xc, int first_layer) {
  int ct = threadIdx.x >> 6, lane = threadIdx.x & 63;
  int m = lane & 15, q = lane >> 4;
  const unsigned short* arow = ah + (size_t)(b * NN + m) * AHS + q * 8;
  const bf16x8* B = (const bf16x8*)wfl + lane;
  floatx4 acc = (floatx4){0.f, 0.f, 0.f, 0.f};
#pragma unroll
  for (int kc = 0; kc < 8; ++kc) {
    int koff = (kc < 4) ? kc * 32 : hoff_in + (kc - 4) * 32;
    bf16x8 a0 = *(const bf16x8*)(arow + koff);
    bf16x8 bb = B[(kc * 8 + ct) * 64];
    acc = __builtin_amdgcn_mfma_f32_16x16x32_bf16(a0, bb, acc, 0, 0, 0);
  }
  int col = ct * 16 + m;
  float bias = bn[col];
  if (first_layer) {
    float s1[4], s2[4];
#pragma unroll
    for (int r = 0; r < 4; ++r) {
      float v = xc[r] + acc[r] + bias;
      xc[r] = v; s1[r] = v; s2[r] = v * v;
    }
#pragma unroll
    for (int r = 0; r < 4; ++r) {
      s1[r] += __shfl_xor(s1[r], 1); s2[r] += __shfl_xor(s2[r], 1);
      s1[r] += __shfl_xor(s1[r], 2); s2[r] += __shfl_xor(s2[r], 2);
      s1[r] += __shfl_xor(s1[r], 4); s2[r] += __shfl_xor(s2[r], 4);
      s1[r] += __shfl_xor(s1[r], 8); s2[r] += __shfl_xor(s2[r], 8);
    }
    float* red = (float*)redc;
    __syncthreads();
    if (m == 0) {
#pragma unroll
      for (int r = 0; r < 4; ++r) {
        red[(q * 4 + r) * 8 + ct] = s1[r];
        red[128 + (q * 4 + r) * 8 + ct] = s2[r];
      }
    }
    __syncthreads();
#pragma unroll
    for (int r = 0; r < 4; ++r) {
      float t1 = 0.f, t2 = 0.f;
#pragma unroll
      for (int j = 0; j < 8; ++j) {
        t1 += red[(q * 4 + r) * 8 + j];
        t2 += red[128 + (q * 4 + r) * 8 + j];
      }
      float mu = t1 * (1.0f / 128.0f);
      float var = t2 * (1.0f / 128.0f) - mu * mu;
      float rv = rsqrtf(var + 1e-5f);
      float hh = gelu((xc[r] - mu) * rv * gamma[col] + beta[col]);
      ah[(size_t)(b * NN + q * 4 + r) * AHS + 256 + col] = f2bf(hh);
    }
  } else {
#pragma unroll
    for (int r = 0; r < 4; ++r)
      x[(size_t)(b * NN + q * 4 + r) * DD + col] = xc[r] + acc[r] + bias;
  }
}

// ---------------------------------------------------------------------------
// Megakernel: 8 XCD-affine groups x 32 blocks (group = bid&7 = batch).
// 2 group barriers + 16-flag wait (block gb==0 only).
__global__ __launch_bounds__(NT, 1) void k_mega(
    const float* __restrict__ elements, const float* __restrict__ ln_gamma,
    const float* __restrict__ ln_beta, const float* __restrict__ w_nei,
    const float* __restrict__ b_nei, const float* __restrict__ w_root,
    const int* __restrict__ srcv, const int* __restrict__ dstv, int E,
    float* __restrict__ x, int* s0a, int* s1a, float* lvl4, float* sroot,
    unsigned short* wf, unsigned short* ah, int* bar) {
  __shared__ __align__(16) char smem[65536];
  int bid = blockIdx.x, tid = threadIdx.x;
  int b = bid & 7, gb = bid >> 3;    // XCD-affine: batch = bid % 8
  int Eb = E >> 3;
  unsigned short* wfg = wf + (size_t)b * 65536;
  float xcl[8], xci[16], xct[4];

  // ---- P0: tree (gb 0-15, stashes xci) || CSR (16-23) || repack (24-31) ----
  if (gb < 16) {
    ph_tree(smem, b, gb, elements, x, lvl4, ah, ln_gamma, ln_beta, sroot, xci);
  } else if (gb < 24) {
    int base = b * Eb;
    for (int i = base + (gb - 16) * NT + tid; i < base + Eb; i += 8 * NT) {
      int dv = dstv[i];
      if (i == 0 || dstv[i - 1] != dv) s0a[dv] = i;
      if (i == base + Eb - 1 || dstv[i + 1] != dv) s1a[dv] = i + 1;
    }
  } else {
    int gi = (gb - 24) * NT + tid;   // 0..4095 frag units
    int lane = gi & 63, ct = (gi >> 6) & 7, kc = gi >> 9;
    int n = ct * 16 + (lane & 15);
    int k = kc * 32 + (lane >> 4) * 8;
    int kk = k & 127;
#pragma unroll
    for (int l = 0; l < 2; ++l) {
      const float* w = (k < 128) ? (w_nei + (size_t)l * DD * DD)
                                 : (w_root + (size_t)l * DD * DD);
      unsigned short* o = wfg + (size_t)l * 32768 + (size_t)gi * 8;
#pragma unroll
      for (int j = 0; j < 8; ++j) o[j] = f2bf(w[(size_t)(kk + j) * DD + n]);
    }
  }
  gbarN(bar, 0);

  // ---- P1 (layer 0) ----
  if (gb == 0) {
    ph_top(smem, b, lvl4, ah, ln_gamma, ln_beta);      // xs in LDS, h->ah
    {                                                  // stash xct from xs
      int wv = tid >> 6, ln = tid & 63, m_ = ln & 15, q_ = ln >> 4;
      float (*xs)[DD] = (float(*)[DD])smem;
#pragma unroll
      for (int r = 0; r < 4; ++r) xct[r] = xs[q_ * 4 + r][wv * 16 + m_];
    }
    if (tid < 128) ph_topfin(b, sroot, ah, 128);
    __syncthreads();
    ph_gemm16t(smem + 61440, b, ah, wfg, b_nei, x, 128,
               ln_gamma + DD, ln_beta + DD, xct, 1);
    __syncthreads();
  }
  ph_leafagg(smem, b, gb, srcv, s0a, s1a, ah, 128, lvl4, ln_gamma, ln_beta, 1);
  __syncthreads();
  ph_gemm32(smem + 61440, b * NN + 1024 + gb * 32, ah, wfg, b_nei, x, 128,
            ln_gamma + DD, ln_beta + DD, xcl, 1);
  if (gb < 16) {
    ph_gemm32s(smem + 61440, b, gb, 0, ah, wfg, b_nei, x, 128,
               ln_gamma + DD, ln_beta + DD, xci, 1);
    ph_gemm32s(smem + 61440, b, gb, 32, ah, wfg, b_nei, x, 128,
               ln_gamma + DD, ln_beta + DD, xci + 8, 1);
  }
  gbarN(bar, 1);

  // ---- P2 (layer 1): no group barrier; only block gb==0 waits on 16 flags --
  if (gb < 16) {
    ph_aggsub(smem, b, gb, ah, sroot);
    __syncthreads();
    if (tid == 0) {
      __threadfence();
      __hip_atomic_store(bar + 1024 + b * 64 + gb * 4, 1, __ATOMIC_RELAXED,
                         __HIP_MEMORY_SCOPE_AGENT);
    }
  }
  ph_leafagg(smem, b, gb, srcv, s0a, s1a, ah, 256, lvl4, ln_gamma, ln_beta, 0);
  __syncthreads();
  ph_gemm32(smem + 61440, b * NN + 1024 + gb * 32, ah, wfg + 32768, b_nei + DD,
            x, 256, ln_gamma, ln_beta, xcl, 0);
  if (gb < 16) {
    ph_gemm32s(smem + 61440, b, gb, 0, ah, wfg + 32768, b_nei + DD, x, 256,
               ln_gamma, ln_beta, xci, 0);
    ph_gemm32s(smem + 61440, b, gb, 32, ah, wfg + 32768, b_nei + DD, x, 256,
               ln_gamma, ln_beta, xci + 8, 0);
  }
  if (gb == 0) {
    if (tid < 16) {
      while (!__hip_atomic_load(bar + 1024 + b * 64 + tid * 4, __ATOMIC_RELAXED,
                                __HIP_MEMORY_SCOPE_AGENT))
        __builtin_amdgcn_s_sleep(1);
      __threadfence();
    }
    __syncthreads();
    if (tid < 128) ph_topfin(b, sroot, ah, 256);
    __syncthreads();
    ph_gemm16t(smem + 61440, b, ah, wfg + 32768, b_nei + DD, x, 256,
               ln_gamma, ln_beta, xct, 0);
  }
}

// ---------------------------------------------------------------------------
extern "C" void kernel_launch(void* const* d_in, const int* in_sizes, int n_in,
                              void* d_out, int out_size, void* d_ws, size_t ws_size,
                              hipStream_t stream) {
  const float* elements = (const float*)d_in[0];
  const float* ln_gamma = (const float*)d_in[1];
  const float* ln_beta  = (const float*)d_in[2];
  const float* w_nei    = (const float*)d_in[3];
  const float* b_nei    = (const float*)d_in[4];
  const float* w_root   = (const float*)d_in[5];
  const int*   edge     = (const int*)d_in[6];
  int E = in_sizes[6] / 2;
  const int* srcv = edge;
  const int* dstv = edge + E;
  float* x = (float*)d_out;

  char* ws = (char*)d_ws;
  int*            bar   = (int*)ws;                         // 8 KB used
  int*            s0    = (int*)(ws + 65536);               // 64 KB
  int*            s1    = (int*)(ws + 131072);              // 64 KB
  float*          lvl4  = (float*)(ws + 196608);            // 64 KB
  float*          sroot = (float*)(ws + 262144);            // 64 KB
  unsigned short* wf    = (unsigned short*)(ws + 327680);   // 1 MB (8 copies)
  unsigned short* ah    = (unsigned short*)(ws + 327680 + 1048576);  // 12.6 MB

  hipMemsetAsync(bar, 0, 8192, stream);
  k_mega<<<dim3(NB), dim3(NT), 0, stream>>>(
      elements, ln_gamma, ln_beta, w_nei, b_nei, w_root,
      srcv, dstv, E, x, s0, s1, lvl4, sroot, wf, ah, bar);
}